// Round 2
// baseline (378.555 us; speedup 1.0000x reference)
//
#include <hip/hip_runtime.h>

// B=64, N=64, D=128, L=4, T=10. Float tensors may arrive as bf16 OR fp32 —
// detected at runtime (flag in ws), canonicalized to fp32 before compute.

typedef _Float16 f16;
typedef _Float16 f16x4 __attribute__((ext_vector_type(4)));
typedef _Float16 f16x8 __attribute__((ext_vector_type(8)));
typedef float f32x4 __attribute__((ext_vector_type(4)));

__device__ __forceinline__ float bf2f(unsigned short u) {
    union { unsigned int i; float f; } v; v.i = ((unsigned int)u) << 16; return v.f;
}
__device__ __forceinline__ unsigned short f2bf(float f) {
    union { float f; unsigned int i; } v; v.f = f;
    unsigned int x = v.i;
    return (unsigned short)((x + 0x7fffu + ((x >> 16) & 1u)) >> 16);
}
__device__ __forceinline__ float silu_f(float x) {
    return x / (1.0f + __expf(-x));
}

struct Ptrs { const void* p[14]; };

// Canonical fp32 layout offsets (floats):
// pos 0 (12288), embed 12288 (1280), ew1 13568 (131584), eb1 145152 (512),
// ew2 145664 (65536), eb2 211200 (512), nw1 211712 (131072), nb1 342784 (512),
// nw2 343296 (65536), nb2 408832 (512), lng 409344 (512), lnb 409856 (512),
// ow 410368 (384), ob 410752 (3). total 410755.
#define CANON_TOTAL 410755

// ---------------------------------------------------------------------------
// dtype detection: even-indexed u16s of positions are real bf16 values iff
// the tensor is bf16 (N(0,1) -> bf16 exponent in [110,135]); for fp32 data
// they are low mantissa bits (uniform exponent, ~10% in range).
// ---------------------------------------------------------------------------
__global__ void detect_kernel(const void* pos, int* flag) {
    int lane = threadIdx.x;   // 64 threads
    const unsigned short* u = (const unsigned short*)pos;
    unsigned short e = u[lane * 2];
    int ex = (e >> 7) & 0xFF;
    int ok = (ex >= 110 && ex <= 135) ? 1 : 0;
#pragma unroll
    for (int m = 1; m < 64; m <<= 1) ok += __shfl_xor(ok, m);
    if (lane == 0) *flag = (ok >= 40) ? 1 : 0;   // 1 = bf16, 0 = fp32
}

__global__ __launch_bounds__(256) void cvt_kernel(Ptrs ptrs, const int* flag, float* canon) {
    int gid = blockIdx.x * 256 + threadIdx.x;
    if (gid >= CANON_TOTAL) return;
    const int off[15] = {0, 12288, 13568, 145152, 145664, 211200, 211712,
                         342784, 343296, 408832, 409344, 409856, 410368,
                         410752, CANON_TOTAL};
    int t = 0;
#pragma unroll
    for (int k = 1; k < 14; k++) if (gid >= off[k]) t = k;
    int i = gid - off[t];
    float v;
    if (*flag) v = bf2f(((const unsigned short*)ptrs.p[t])[i]);
    else       v = ((const float*)ptrs.p[t])[i];
    canon[gid] = v;
}

// ---------------------------------------------------------------------------
// Swizzle weights into f16 B-fragment order for mfma_f32_16x16x32_f16:
//   dst[((s*8+c)*64+l)*8 + j] = W[s*32 + (l>>4)*8 + j][c*16 + (l&15)]
// Per-layer region (f16 elems): wa@0 wb@16K ew2@32K nw1@48K(32K) nw2@80K;
// layer stride 98304; total 393216.
// ---------------------------------------------------------------------------
__global__ __launch_bounds__(256) void swizzle_kernel(const float* canon, f16* dst) {
    int gid = blockIdx.x * 256 + threadIdx.x;   // < 393216
    int lay = gid / 98304;
    int r   = gid % 98304;
    const float* src;
    int rowoff = 0, r2;
    if (r < 49152) {
        int mat = r >> 14; r2 = r & 16383;
        if (mat == 0)      { src = canon + 13568 + lay * 32896; rowoff = 0;   }
        else if (mat == 1) { src = canon + 13568 + lay * 32896; rowoff = 128; }
        else               { src = canon + 145664 + lay * 16384; }
    } else if (r < 81920) {
        r2 = r - 49152; src = canon + 211712 + lay * 32768;
    } else {
        r2 = r - 81920; src = canon + 343296 + lay * 16384;
    }
    int s = r2 >> 12;
    int q = r2 & 4095;
    int j = q & 7, l = (q >> 3) & 63, c = q >> 9;
    int row = rowoff + s * 32 + ((l >> 4) << 3) + j;
    int col = (c << 4) + (l & 15);
    dst[gid] = (f16)src[row * 128 + col];
}

__global__ __launch_bounds__(256) void embed_kernel(
    const int* an, const float* embC, f16* hf16)
{
    int gid = blockIdx.x * 256 + threadIdx.x;   // < 524288
    int row = gid >> 7, d = gid & 127;
    int a = an[row];
    a = a < 0 ? 0 : (a > 9 ? 9 : a);            // defensive clamp
    hf16[gid] = (f16)embC[a * 128 + d];
}

// a = h@wa + eb1, b = h@wb  (f16 outputs). 1 wave, 16 rows per block.
__global__ __launch_bounds__(64) void ab_kernel(
    const f16* hf, const f16* wa_swz, const f16* wb_swz,
    const float* eb1C, f16* aout, f16* bout)
{
    int lane = threadIdx.x;
    int row0 = blockIdx.x << 4;
    int m_ = lane & 15, q_ = lane >> 4;
    f16x8 afrag[4];
#pragma unroll
    for (int s = 0; s < 4; s++)
        afrag[s] = *(const f16x8*)(hf + (row0 + m_) * 128 + s * 32 + q_ * 8);
#pragma unroll
    for (int mat = 0; mat < 2; mat++) {
        const f16* W = mat ? wb_swz : wa_swz;
        f16* out     = mat ? bout : aout;
#pragma unroll
        for (int c = 0; c < 8; c++) {
            float init = mat ? 0.0f : eb1C[c * 16 + m_];
            f32x4 acc = { init, init, init, init };
#pragma unroll
            for (int s = 0; s < 4; s++) {
                f16x8 bfr = *(const f16x8*)(W + ((s * 8 + c) * 64 + lane) * 8);
                acc = __builtin_amdgcn_mfma_f32_16x16x32_f16(afrag[s], bfr, acc, 0, 0, 0);
            }
#pragma unroll
            for (int r = 0; r < 4; r++)
                out[(row0 + q_ * 4 + r) * 128 + c * 16 + m_] = (f16)acc[r];
        }
    }
}

// Block per (b,i): m_i = mean_j silu(silu(pre_ij) @ ew2 + eb2)
__global__ __launch_bounds__(256) void edge_kernel(
    const float* posC, const f16* a16, const f16* b16,
    const float* wdC, const f16* ew2_swz, const float* eb2C, f16* m_out)
{
    __shared__ f16 Wlds[16384];        // swizzled ew2, 32 KB
    __shared__ f16 S[64 * 136];        // silu(pre), padded stride 136
    __shared__ float a_sh[128];
    __shared__ float wd_sh[128];
    __shared__ float dsq_sh[64];
    __shared__ float msum[4][128];

    int t  = threadIdx.x;
    int ig = blockIdx.x;               // global row index (b*64+i)
    int b  = ig >> 6;

#pragma unroll
    for (int k = 0; k < 8; k++) {
        int idx = (k * 256 + t) * 8;
        *(f16x8*)(Wlds + idx) = *(const f16x8*)(ew2_swz + idx);
    }
    if (t < 128) a_sh[t] = (float)a16[ig * 128 + t];     // includes eb1
    else         wd_sh[t - 128] = wdC[t - 128];
    if (t < 64) {
        float xi = posC[ig * 3 + 0];
        float yi = posC[ig * 3 + 1];
        float zi = posC[ig * 3 + 2];
        int jg = b * 64 + t;
        float dx = xi - posC[jg * 3 + 0];
        float dy = yi - posC[jg * 3 + 1];
        float dz = zi - posC[jg * 3 + 2];
        dsq_sh[t] = dx * dx + dy * dy + dz * dz;
    }
    __syncthreads();

    // S[j][d] = silu(a_i[d] + b_j[d] + dsq[j]*wd[d])
    {
        int dj = t >> 5;               // 0..7
        int dbase = (t & 31) * 4;      // 0..124
#pragma unroll
        for (int p = 0; p < 8; p++) {
            int j = p * 8 + dj;
            f16x4 bv = *(const f16x4*)(b16 + (b * 64 + j) * 128 + dbase);
            float ds = dsq_sh[j];
            float p0 = a_sh[dbase + 0] + (float)bv[0] + ds * wd_sh[dbase + 0];
            float p1 = a_sh[dbase + 1] + (float)bv[1] + ds * wd_sh[dbase + 1];
            float p2 = a_sh[dbase + 2] + (float)bv[2] + ds * wd_sh[dbase + 2];
            float p3 = a_sh[dbase + 3] + (float)bv[3] + ds * wd_sh[dbase + 3];
            f16x4 sv = { (f16)silu_f(p0), (f16)silu_f(p1),
                         (f16)silu_f(p2), (f16)silu_f(p3) };
            *(f16x4*)(S + j * 136 + dbase) = sv;
        }
    }
    __syncthreads();

    // GEMM 64x128 @ 128x128: wave w handles S-rows 16w..16w+15, all 128 cols
    int lane = t & 63, w = t >> 6;
    int m_ = lane & 15, q_ = lane >> 4;
    f32x4 acc[8];
#pragma unroll
    for (int c = 0; c < 8; c++) {
        float e = eb2C[c * 16 + m_];
        acc[c] = (f32x4){ e, e, e, e };
    }
#pragma unroll
    for (int s = 0; s < 4; s++) {
        f16x8 af = *(const f16x8*)(S + (w * 16 + m_) * 136 + s * 32 + q_ * 8);
#pragma unroll
        for (int c = 0; c < 8; c++) {
            f16x8 bfr = *(const f16x8*)(Wlds + ((s * 8 + c) * 64 + lane) * 8);
            acc[c] = __builtin_amdgcn_mfma_f32_16x16x32_f16(af, bfr, acc[c], 0, 0, 0);
        }
    }
    // silu + sum over this wave's 16 rows
#pragma unroll
    for (int c = 0; c < 8; c++) {
        float sc = silu_f(acc[c][0]) + silu_f(acc[c][1]) +
                   silu_f(acc[c][2]) + silu_f(acc[c][3]);
        sc += __shfl_xor(sc, 16);
        sc += __shfl_xor(sc, 32);
        if (lane < 16) msum[w][c * 16 + lane] = sc;
    }
    __syncthreads();
    if (t < 128) {
        float mv = (msum[0][t] + msum[1][t] + msum[2][t] + msum[3][t]) * (1.0f / 64.0f);
        m_out[ig * 128 + t] = (f16)mv;
    }
}

// u = silu([h|m] @ nw1 + nb1)   (K=256)
__global__ __launch_bounds__(64) void n1_kernel(
    const f16* hf, const f16* mf, const f16* nw1_swz,
    const float* nb1C, f16* uf)
{
    int lane = threadIdx.x;
    int row0 = blockIdx.x << 4;
    int m_ = lane & 15, q_ = lane >> 4;
    f16x8 afrag[8];
#pragma unroll
    for (int s = 0; s < 4; s++) {
        afrag[s]     = *(const f16x8*)(hf + (row0 + m_) * 128 + s * 32 + q_ * 8);
        afrag[s + 4] = *(const f16x8*)(mf + (row0 + m_) * 128 + s * 32 + q_ * 8);
    }
#pragma unroll
    for (int c = 0; c < 8; c++) {
        float e = nb1C[c * 16 + m_];
        f32x4 acc = { e, e, e, e };
#pragma unroll
        for (int s = 0; s < 8; s++) {
            f16x8 bfr = *(const f16x8*)(nw1_swz + ((s * 8 + c) * 64 + lane) * 8);
            acc = __builtin_amdgcn_mfma_f32_16x16x32_f16(afrag[s], bfr, acc, 0, 0, 0);
        }
#pragma unroll
        for (int r = 0; r < 4; r++)
            uf[(row0 + q_ * 4 + r) * 128 + c * 16 + m_] = (f16)silu_f(acc[r]);
    }
}

// x = h + u@nw2 + nb2 ; h_new = LN(x)*g + b
__global__ __launch_bounds__(64) void n2_kernel(
    const f16* uf, const f16* nw2_swz, const float* nb2C,
    const float* lngC, const float* lnbC, f16* hf16)
{
    int lane = threadIdx.x;
    int row0 = blockIdx.x << 4;
    int m_ = lane & 15, q_ = lane >> 4;
    f16x8 afrag[4];
#pragma unroll
    for (int s = 0; s < 4; s++)
        afrag[s] = *(const f16x8*)(uf + (row0 + m_) * 128 + s * 32 + q_ * 8);
    float x[8][4];
#pragma unroll
    for (int c = 0; c < 8; c++) {
        float e = nb2C[c * 16 + m_];
        f32x4 acc = { e, e, e, e };
#pragma unroll
        for (int s = 0; s < 4; s++) {
            f16x8 bfr = *(const f16x8*)(nw2_swz + ((s * 8 + c) * 64 + lane) * 8);
            acc = __builtin_amdgcn_mfma_f32_16x16x32_f16(afrag[s], bfr, acc, 0, 0, 0);
        }
#pragma unroll
        for (int r = 0; r < 4; r++)
            x[c][r] = acc[r] + (float)hf16[(row0 + q_ * 4 + r) * 128 + c * 16 + m_];
    }
#pragma unroll
    for (int r = 0; r < 4; r++) {
        float s1 = 0.0f, s2 = 0.0f;
#pragma unroll
        for (int c = 0; c < 8; c++) { s1 += x[c][r]; s2 += x[c][r] * x[c][r]; }
#pragma unroll
        for (int msk = 1; msk < 16; msk <<= 1) {
            s1 += __shfl_xor(s1, msk);
            s2 += __shfl_xor(s2, msk);
        }
        float mu  = s1 * (1.0f / 128.0f);
        float var = s2 * (1.0f / 128.0f) - mu * mu;
        float rs  = rsqrtf(var + 1e-5f);
        int row = row0 + q_ * 4 + r;
#pragma unroll
        for (int c = 0; c < 8; c++) {
            int col = c * 16 + m_;
            float y = (x[c][r] - mu) * rs * lngC[col] + lnbC[col];
            hf16[row * 128 + col] = (f16)y;
        }
    }
}

__global__ __launch_bounds__(256) void out_kernel(
    const f16* hf, const float* owC, const float* obC,
    const int* flag, void* out)
{
    int row = blockIdx.x * 256 + threadIdx.x;   // < 4096
    float a0 = obC[0], a1 = obC[1], a2 = obC[2];
    for (int d = 0; d < 128; d++) {
        float h = (float)hf[row * 128 + d];
        a0 += h * owC[d * 3 + 0];
        a1 += h * owC[d * 3 + 1];
        a2 += h * owC[d * 3 + 2];
    }
    if (*flag) {
        unsigned short* o = (unsigned short*)out;
        o[row * 3 + 0] = f2bf(a0);
        o[row * 3 + 1] = f2bf(a1);
        o[row * 3 + 2] = f2bf(a2);
    } else {
        float* o = (float*)out;
        o[row * 3 + 0] = a0;
        o[row * 3 + 1] = a1;
        o[row * 3 + 2] = a2;
    }
}

extern "C" void kernel_launch(void* const* d_in, const int* in_sizes, int n_in,
                              void* d_out, int out_size, void* d_ws, size_t ws_size,
                              hipStream_t stream)
{
    const int* an = (const int*)d_in[1];

    char* ws = (char*)d_ws;
    int*   flag  = (int*)ws;
    float* canon = (float*)(ws + 1024);             // 1.57 MB
    f16*   h16   = (f16*)(ws + (2u << 20));         // 1 MB
    f16*   a16   = (f16*)(ws + (3u << 20));         // 1 MB
    f16*   b16   = (f16*)(ws + (4u << 20));         // 1 MB
    f16*   m16   = (f16*)(ws + (5u << 20));         // 1 MB
    f16*   u16b  = (f16*)(ws + (6u << 20));         // 1 MB
    f16*   Wswz  = (f16*)(ws + (7u << 20));         // 768 KB  (total < 7.75 MB)

    Ptrs ptrs;
    const int src_idx[14] = {0, 2, 3, 4, 5, 6, 7, 8, 9, 10, 11, 12, 13, 14};
    for (int k = 0; k < 14; k++) ptrs.p[k] = d_in[src_idx[k]];

    detect_kernel<<<1, 64, 0, stream>>>(d_in[0], flag);
    cvt_kernel<<<1605, 256, 0, stream>>>(ptrs, flag, canon);
    swizzle_kernel<<<1536, 256, 0, stream>>>(canon, Wswz);
    embed_kernel<<<2048, 256, 0, stream>>>(an, canon + 12288, h16);

    for (int lay = 0; lay < 4; lay++) {
        const f16* wl = Wswz + lay * 98304;
        const float* eb1C = canon + 145152 + lay * 128;
        const float* wdC  = canon + 13568 + lay * 32896 + 32768;  // ew1 row 256
        const float* eb2C = canon + 211200 + lay * 128;
        const float* nb1C = canon + 342784 + lay * 128;
        const float* nb2C = canon + 408832 + lay * 128;
        const float* lngC = canon + 409344 + lay * 128;
        const float* lnbC = canon + 409856 + lay * 128;

        ab_kernel<<<256, 64, 0, stream>>>(h16, wl, wl + 16384, eb1C, a16, b16);
        edge_kernel<<<4096, 256, 0, stream>>>(canon /*pos*/, a16, b16,
                                              wdC, wl + 32768, eb2C, m16);
        n1_kernel<<<256, 64, 0, stream>>>(h16, m16, wl + 49152, nb1C, u16b);
        n2_kernel<<<256, 64, 0, stream>>>(u16b, wl + 81920, nb2C, lngC, lnbC, h16);
    }
    out_kernel<<<16, 256, 0, stream>>>(h16, canon + 410368, canon + 410752,
                                       flag, d_out);
}

// Round 3
// 300.349 us; speedup vs baseline: 1.2604x; 1.2604x over previous
//
#include <hip/hip_runtime.h>

// B=64, N=64, D=128, L=4, T=10. Float tensors may arrive as bf16 OR fp32 —
// detected at runtime (flag in ws), canonicalized before compute.

typedef _Float16 f16;
typedef _Float16 f16x4 __attribute__((ext_vector_type(4)));
typedef _Float16 f16x8 __attribute__((ext_vector_type(8)));
typedef float f32x4 __attribute__((ext_vector_type(4)));

__device__ __forceinline__ float bf2f(unsigned short u) {
    union { unsigned int i; float f; } v; v.i = ((unsigned int)u) << 16; return v.f;
}
__device__ __forceinline__ unsigned short f2bf(float f) {
    union { float f; unsigned int i; } v; v.f = f;
    unsigned int x = v.i;
    return (unsigned short)((x + 0x7fffu + ((x >> 16) & 1u)) >> 16);
}
// fast silu: 5 instrs (mul, v_exp_f32, add, v_rcp_f32, mul) vs ~13 for x/(1+expf)
__device__ __forceinline__ float silu_f(float x) {
    float e = __builtin_amdgcn_exp2f(-1.44269504088896f * x);
    return x * __builtin_amdgcn_rcpf(1.0f + e);
}

struct Ptrs { const void* p[14]; };
// p: 0 pos, 1 embed, 2 ew1, 3 eb1, 4 ew2, 5 eb2, 6 nw1, 7 nb1, 8 nw2,
//    9 nb2, 10 lng, 11 lnb, 12 ow, 13 ob

__device__ __forceinline__ float ldf(const void* p, int i, int bf) {
    return bf ? bf2f(((const unsigned short*)p)[i]) : ((const float*)p)[i];
}

// small canon (fp32) offsets: pos 0(12288) embed 12288(1280) wd 13568(512)
// eb1 14080 eb2 14592 nb1 15104 nb2 15616 lng 16128 lnb 16640 (512 each)
// ow 17152(384) ob 17536(3). total 17539.
#define SWZ_TOTAL 393216
#define SMALL_TOTAL 17539

__global__ void detect_kernel(const void* pos, int* flag) {
    int lane = threadIdx.x;   // 64 threads
    const unsigned short* u = (const unsigned short*)pos;
    int ex = (u[lane * 2] >> 7) & 0xFF;
    int ok = (ex >= 110 && ex <= 135) ? 1 : 0;
#pragma unroll
    for (int m = 1; m < 64; m <<= 1) ok += __shfl_xor(ok, m);
    if (lane == 0) *flag = (ok >= 40) ? 1 : 0;   // 1 = bf16, 0 = fp32
}

// Swizzle weights into f16 B-fragment order for mfma_f32_16x16x32_f16:
//   dst[((s*8+c)*64+l)*8 + j] = W[s*32 + (l>>4)*8 + j][c*16 + (l&15)]
// Per-layer: wa@0 wb@16K ew2@32K nw1@48K(32K) nw2@80K; stride 98304.
// Plus small-tensor fp32 canonicalization (tail of the grid).
__global__ __launch_bounds__(256) void prep_kernel(
    Ptrs ptrs, const int* flag, f16* dst, float* sc)
{
    int gid = blockIdx.x * 256 + threadIdx.x;
    int bf = *flag;
    if (gid < SWZ_TOTAL) {
        int lay = gid / 98304;
        int r   = gid % 98304;
        const void* src; int base, rowoff = 0, r2;
        if (r < 49152) {
            int mat = r >> 14; r2 = r & 16383;
            if (mat == 0)      { src = ptrs.p[2]; base = lay * 32896; }
            else if (mat == 1) { src = ptrs.p[2]; base = lay * 32896; rowoff = 128; }
            else               { src = ptrs.p[4]; base = lay * 16384; }
        } else if (r < 81920) {
            r2 = r - 49152; src = ptrs.p[6]; base = lay * 32768;
        } else {
            r2 = r - 81920; src = ptrs.p[8]; base = lay * 16384;
        }
        int s = r2 >> 12, q = r2 & 4095;
        int j = q & 7, l = (q >> 3) & 63, c = q >> 9;
        int row = rowoff + s * 32 + ((l >> 4) << 3) + j;
        int col = (c << 4) + (l & 15);
        dst[gid] = (f16)ldf(src, base + row * 128 + col, bf);
    } else {
        int sid = gid - SWZ_TOTAL;
        if (sid >= SMALL_TOTAL) return;
        const void* src; int i;
        if      (sid < 12288) { src = ptrs.p[0]; i = sid; }
        else if (sid < 13568) { src = ptrs.p[1]; i = sid - 12288; }
        else if (sid < 14080) { int k = sid - 13568;
                                src = ptrs.p[2]; i = (k >> 7) * 32896 + 32768 + (k & 127); }
        else if (sid < 14592) { src = ptrs.p[3];  i = sid - 14080; }
        else if (sid < 15104) { src = ptrs.p[5];  i = sid - 14592; }
        else if (sid < 15616) { src = ptrs.p[7];  i = sid - 15104; }
        else if (sid < 16128) { src = ptrs.p[9];  i = sid - 15616; }
        else if (sid < 16640) { src = ptrs.p[10]; i = sid - 16128; }
        else if (sid < 17152) { src = ptrs.p[11]; i = sid - 16640; }
        else if (sid < 17536) { src = ptrs.p[12]; i = sid - 17152; }
        else                  { src = ptrs.p[13]; i = sid - 17536; }
        sc[sid] = ldf(src, i, bf);
    }
}

// h = embed[an] ; a = h@wa + eb1 ; b = h@wb.  1 wave / 16 rows.
__global__ __launch_bounds__(64) void embed_ab_kernel(
    const int* an, const float* sc, const f16* wa, const f16* wb,
    const float* eb1C, f16* h16, f16* a16, f16* b16)
{
    int lane = threadIdx.x;
    int row0 = blockIdx.x << 4;
    int m_ = lane & 15, q_ = lane >> 4;
    const float* emb = sc + 12288;
    int a = an[row0 + m_];
    a = a < 0 ? 0 : (a > 9 ? 9 : a);
    f16x8 afrag[4];
#pragma unroll
    for (int s = 0; s < 4; s++) {
        f32x4 u0 = *(const f32x4*)(emb + a * 128 + s * 32 + q_ * 8);
        f32x4 u1 = *(const f32x4*)(emb + a * 128 + s * 32 + q_ * 8 + 4);
        f16x8 hv;
#pragma unroll
        for (int e = 0; e < 4; e++) { hv[e] = (f16)u0[e]; hv[e + 4] = (f16)u1[e]; }
        afrag[s] = hv;
        *(f16x8*)(h16 + (row0 + m_) * 128 + s * 32 + q_ * 8) = hv;
    }
#pragma unroll
    for (int mat = 0; mat < 2; mat++) {
        const f16* W = mat ? wb : wa;
        f16* out     = mat ? b16 : a16;
#pragma unroll
        for (int c = 0; c < 8; c++) {
            float init = mat ? 0.0f : eb1C[c * 16 + m_];
            f32x4 acc = { init, init, init, init };
#pragma unroll
            for (int s = 0; s < 4; s++) {
                f16x8 bfr = *(const f16x8*)(W + ((s * 8 + c) * 64 + lane) * 8);
                acc = __builtin_amdgcn_mfma_f32_16x16x32_f16(afrag[s], bfr, acc, 0, 0, 0);
            }
#pragma unroll
            for (int r = 0; r < 4; r++)
                out[(row0 + q_ * 4 + r) * 128 + c * 16 + m_] = (f16)acc[r];
        }
    }
}

// Block per (b,i): m_i = mean_j silu(silu(pre_ij) @ ew2 + eb2)
__global__ __launch_bounds__(256) void edge_kernel(
    const float* sc, const f16* a16, const f16* b16,
    const f16* ew2_swz, const float* eb2C, const float* wdC, f16* m_out)
{
    __shared__ f16 Wlds[16384];        // swizzled ew2, 32 KB
    __shared__ f16 S[64 * 136];        // silu(pre), stride 136 (272 B, 16B-aligned)
    __shared__ float a_sh[128];
    __shared__ float wd_sh[128];
    __shared__ float dsq_sh[64];
    __shared__ float msum[4][128];

    int t  = threadIdx.x;
    int ig = blockIdx.x;               // b*64 + i
    int b  = ig >> 6;
    const float* posC = sc;

#pragma unroll
    for (int k = 0; k < 8; k++) {
        int idx = (k * 256 + t) * 8;
        *(f16x8*)(Wlds + idx) = *(const f16x8*)(ew2_swz + idx);
    }
    if (t < 128) a_sh[t] = (float)a16[ig * 128 + t];     // includes eb1
    else         wd_sh[t - 128] = wdC[t - 128];
    if (t < 64) {
        float xi = posC[ig * 3 + 0], yi = posC[ig * 3 + 1], zi = posC[ig * 3 + 2];
        int jg = b * 64 + t;
        float dx = xi - posC[jg * 3 + 0];
        float dy = yi - posC[jg * 3 + 1];
        float dz = zi - posC[jg * 3 + 2];
        dsq_sh[t] = dx * dx + dy * dy + dz * dz;
    }
    __syncthreads();

    // S[j][d] = silu(a_i[d] + b_j[d] + dsq[j]*wd[d])
    // thread -> 8-col chunk (t&15), rows j = (t>>4) + 16k
    {
        int cidx = (t & 15) * 8, jg = t >> 4;
        float a8[8], wd8[8];
        *(f32x4*)&a8[0]  = *(const f32x4*)&a_sh[cidx];
        *(f32x4*)&a8[4]  = *(const f32x4*)&a_sh[cidx + 4];
        *(f32x4*)&wd8[0] = *(const f32x4*)&wd_sh[cidx];
        *(f32x4*)&wd8[4] = *(const f32x4*)&wd_sh[cidx + 4];
#pragma unroll
        for (int k = 0; k < 4; k++) {
            int j = jg + 16 * k;
            float ds = dsq_sh[j];
            f16x8 bv = *(const f16x8*)(b16 + (b * 64 + j) * 128 + cidx);
            f16x8 sv;
#pragma unroll
            for (int e = 0; e < 8; e++) {
                float p = __builtin_fmaf(ds, wd8[e], a8[e] + (float)bv[e]);
                sv[e] = (f16)silu_f(p);
            }
            *(f16x8*)(S + j * 136 + cidx) = sv;
        }
    }
    __syncthreads();

    // GEMM 64x128 @ 128x128: wave w -> S-rows 16w..16w+15, all 128 cols
    int lane = t & 63, w = t >> 6;
    int m_ = lane & 15, q_ = lane >> 4;
    f32x4 acc[8];
#pragma unroll
    for (int c = 0; c < 8; c++) {
        float e = eb2C[c * 16 + m_];
        acc[c] = (f32x4){ e, e, e, e };
    }
#pragma unroll
    for (int s = 0; s < 4; s++) {
        f16x8 af = *(const f16x8*)(S + (w * 16 + m_) * 136 + s * 32 + q_ * 8);
#pragma unroll
        for (int c = 0; c < 8; c++) {
            f16x8 bfr = *(const f16x8*)(Wlds + ((s * 8 + c) * 64 + lane) * 8);
            acc[c] = __builtin_amdgcn_mfma_f32_16x16x32_f16(af, bfr, acc[c], 0, 0, 0);
        }
    }
    // silu + sum over this wave's 16 rows
#pragma unroll
    for (int c = 0; c < 8; c++) {
        float scv = silu_f(acc[c][0]) + silu_f(acc[c][1]) +
                    silu_f(acc[c][2]) + silu_f(acc[c][3]);
        scv += __shfl_xor(scv, 16);
        scv += __shfl_xor(scv, 32);
        if (lane < 16) msum[w][c * 16 + lane] = scv;
    }
    __syncthreads();
    if (t < 128) {
        float mv = (msum[0][t] + msum[1][t] + msum[2][t] + msum[3][t]) * (1.0f / 64.0f);
        m_out[ig * 128 + t] = (f16)mv;
    }
}

// Fused node update: u=silu([h|m]@nw1+nb1); x=h+u@nw2+nb2; h'=LN(x)*g+b;
// then next layer's a=h'@wa+eb1, b=h'@wb.  1 wave / 16 rows, no barriers.
__global__ __launch_bounds__(64) void node_mid_kernel(
    const f16* h16, const f16* m16, const f16* nw1s, const f16* nw2s,
    const float* nb1C, const float* nb2C, const float* lngC, const float* lnbC,
    const f16* waN, const f16* wbN, const float* eb1N,
    f16* a16, f16* b16)
{
    __shared__ f16 relay[16 * 136];
    int lane = threadIdx.x;
    int row0 = blockIdx.x << 4;
    int m_ = lane & 15, q_ = lane >> 4;

    f16x8 af[8];
#pragma unroll
    for (int s = 0; s < 4; s++) {
        af[s]     = *(const f16x8*)(h16 + (row0 + m_) * 128 + s * 32 + q_ * 8);
        af[s + 4] = *(const f16x8*)(m16 + (row0 + m_) * 128 + s * 32 + q_ * 8);
    }
    // n1 -> u in relay
#pragma unroll
    for (int c = 0; c < 8; c++) {
        float e = nb1C[c * 16 + m_];
        f32x4 acc = { e, e, e, e };
#pragma unroll
        for (int s = 0; s < 8; s++) {
            f16x8 bfr = *(const f16x8*)(nw1s + ((s * 8 + c) * 64 + lane) * 8);
            acc = __builtin_amdgcn_mfma_f32_16x16x32_f16(af[s], bfr, acc, 0, 0, 0);
        }
#pragma unroll
        for (int r = 0; r < 4; r++)
            relay[(q_ * 4 + r) * 136 + c * 16 + m_] = (f16)silu_f(acc[r]);
    }
    f16x8 uf[4];
#pragma unroll
    for (int s = 0; s < 4; s++)
        uf[s] = *(const f16x8*)(relay + m_ * 136 + s * 32 + q_ * 8);
    // n2 + residual
    float x[8][4];
#pragma unroll
    for (int c = 0; c < 8; c++) {
        float e = nb2C[c * 16 + m_];
        f32x4 acc = { e, e, e, e };
#pragma unroll
        for (int s = 0; s < 4; s++) {
            f16x8 bfr = *(const f16x8*)(nw2s + ((s * 8 + c) * 64 + lane) * 8);
            acc = __builtin_amdgcn_mfma_f32_16x16x32_f16(uf[s], bfr, acc, 0, 0, 0);
        }
#pragma unroll
        for (int r = 0; r < 4; r++)
            x[c][r] = acc[r] + (float)h16[(row0 + q_ * 4 + r) * 128 + c * 16 + m_];
    }
    // LayerNorm + write h' (global + relay for re-layout)
#pragma unroll
    for (int r = 0; r < 4; r++) {
        float s1 = 0.0f, s2 = 0.0f;
#pragma unroll
        for (int c = 0; c < 8; c++) { s1 += x[c][r]; s2 += x[c][r] * x[c][r]; }
#pragma unroll
        for (int msk = 1; msk < 16; msk <<= 1) {
            s1 += __shfl_xor(s1, msk);
            s2 += __shfl_xor(s2, msk);
        }
        float mu  = s1 * (1.0f / 128.0f);
        float var = s2 * (1.0f / 128.0f) - mu * mu;
        float rs  = rsqrtf(var + 1e-5f);
        int row = row0 + q_ * 4 + r;
#pragma unroll
        for (int c = 0; c < 8; c++) {
            int col = c * 16 + m_;
            float y = (x[c][r] - mu) * rs * lngC[col] + lnbC[col];
            ((f16*)h16)[row * 128 + col] = (f16)y;
            relay[(q_ * 4 + r) * 136 + col] = (f16)y;
        }
    }
    f16x8 hf[4];
#pragma unroll
    for (int s = 0; s < 4; s++)
        hf[s] = *(const f16x8*)(relay + m_ * 136 + s * 32 + q_ * 8);
    // next layer a,b
#pragma unroll
    for (int mat = 0; mat < 2; mat++) {
        const f16* W = mat ? wbN : waN;
        f16* out     = mat ? b16 : a16;
#pragma unroll
        for (int c = 0; c < 8; c++) {
            float init = mat ? 0.0f : eb1N[c * 16 + m_];
            f32x4 acc = { init, init, init, init };
#pragma unroll
            for (int s = 0; s < 4; s++) {
                f16x8 bfr = *(const f16x8*)(W + ((s * 8 + c) * 64 + lane) * 8);
                acc = __builtin_amdgcn_mfma_f32_16x16x32_f16(hf[s], bfr, acc, 0, 0, 0);
            }
#pragma unroll
            for (int r = 0; r < 4; r++)
                out[(row0 + q_ * 4 + r) * 128 + c * 16 + m_] = (f16)acc[r];
        }
    }
}

// Last layer: node update then out = h'@ow + ob
__global__ __launch_bounds__(64) void node_final_kernel(
    const f16* h16, const f16* m16, const f16* nw1s, const f16* nw2s,
    const float* nb1C, const float* nb2C, const float* lngC, const float* lnbC,
    const float* owC, const float* obC, const int* flag, void* out)
{
    __shared__ f16 relay[16 * 136];
    int lane = threadIdx.x;
    int row0 = blockIdx.x << 4;
    int m_ = lane & 15, q_ = lane >> 4;

    f16x8 af[8];
#pragma unroll
    for (int s = 0; s < 4; s++) {
        af[s]     = *(const f16x8*)(h16 + (row0 + m_) * 128 + s * 32 + q_ * 8);
        af[s + 4] = *(const f16x8*)(m16 + (row0 + m_) * 128 + s * 32 + q_ * 8);
    }
#pragma unroll
    for (int c = 0; c < 8; c++) {
        float e = nb1C[c * 16 + m_];
        f32x4 acc = { e, e, e, e };
#pragma unroll
        for (int s = 0; s < 8; s++) {
            f16x8 bfr = *(const f16x8*)(nw1s + ((s * 8 + c) * 64 + lane) * 8);
            acc = __builtin_amdgcn_mfma_f32_16x16x32_f16(af[s], bfr, acc, 0, 0, 0);
        }
#pragma unroll
        for (int r = 0; r < 4; r++)
            relay[(q_ * 4 + r) * 136 + c * 16 + m_] = (f16)silu_f(acc[r]);
    }
    f16x8 uf[4];
#pragma unroll
    for (int s = 0; s < 4; s++)
        uf[s] = *(const f16x8*)(relay + m_ * 136 + s * 32 + q_ * 8);
    float x[8][4];
#pragma unroll
    for (int c = 0; c < 8; c++) {
        float e = nb2C[c * 16 + m_];
        f32x4 acc = { e, e, e, e };
#pragma unroll
        for (int s = 0; s < 4; s++) {
            f16x8 bfr = *(const f16x8*)(nw2s + ((s * 8 + c) * 64 + lane) * 8);
            acc = __builtin_amdgcn_mfma_f32_16x16x32_f16(uf[s], bfr, acc, 0, 0, 0);
        }
#pragma unroll
        for (int r = 0; r < 4; r++)
            x[c][r] = acc[r] + (float)h16[(row0 + q_ * 4 + r) * 128 + c * 16 + m_];
    }
    int bf = *flag;
#pragma unroll
    for (int r = 0; r < 4; r++) {
        float s1 = 0.0f, s2 = 0.0f;
#pragma unroll
        for (int c = 0; c < 8; c++) { s1 += x[c][r]; s2 += x[c][r] * x[c][r]; }
#pragma unroll
        for (int msk = 1; msk < 16; msk <<= 1) {
            s1 += __shfl_xor(s1, msk);
            s2 += __shfl_xor(s2, msk);
        }
        float mu  = s1 * (1.0f / 128.0f);
        float var = s2 * (1.0f / 128.0f) - mu * mu;
        float rs  = rsqrtf(var + 1e-5f);
        float p0 = 0.0f, p1 = 0.0f, p2 = 0.0f;
#pragma unroll
        for (int c = 0; c < 8; c++) {
            int col = c * 16 + m_;
            float y = (x[c][r] - mu) * rs * lngC[col] + lnbC[col];
            p0 += y * owC[col * 3 + 0];
            p1 += y * owC[col * 3 + 1];
            p2 += y * owC[col * 3 + 2];
        }
#pragma unroll
        for (int msk = 1; msk < 16; msk <<= 1) {
            p0 += __shfl_xor(p0, msk);
            p1 += __shfl_xor(p1, msk);
            p2 += __shfl_xor(p2, msk);
        }
        if (m_ == 0) {
            int row = row0 + q_ * 4 + r;
            p0 += obC[0]; p1 += obC[1]; p2 += obC[2];
            if (bf) {
                unsigned short* o = (unsigned short*)out;
                o[row * 3 + 0] = f2bf(p0);
                o[row * 3 + 1] = f2bf(p1);
                o[row * 3 + 2] = f2bf(p2);
            } else {
                float* o = (float*)out;
                o[row * 3 + 0] = p0;
                o[row * 3 + 1] = p1;
                o[row * 3 + 2] = p2;
            }
        }
    }
}

extern "C" void kernel_launch(void* const* d_in, const int* in_sizes, int n_in,
                              void* d_out, int out_size, void* d_ws, size_t ws_size,
                              hipStream_t stream)
{
    const int* an = (const int*)d_in[1];

    char* ws = (char*)d_ws;
    int*   flag = (int*)ws;
    float* sc   = (float*)(ws + 1024);              // 70 KB
    f16*   Wswz = (f16*)(ws + (128u << 10));        // 768 KB
    f16*   h16  = (f16*)(ws + (1u << 20));          // 1 MB
    f16*   a16  = (f16*)(ws + (2u << 20));
    f16*   b16  = (f16*)(ws + (3u << 20));
    f16*   m16  = (f16*)(ws + (4u << 20));          // total 5 MB

    Ptrs ptrs;
    const int src_idx[14] = {0, 2, 3, 4, 5, 6, 7, 8, 9, 10, 11, 12, 13, 14};
    for (int k = 0; k < 14; k++) ptrs.p[k] = d_in[src_idx[k]];

    detect_kernel<<<1, 64, 0, stream>>>(d_in[0], flag);
    prep_kernel<<<1605, 256, 0, stream>>>(ptrs, flag, Wswz, sc);
    embed_ab_kernel<<<256, 64, 0, stream>>>(an, sc, Wswz, Wswz + 16384,
                                            sc + 14080, h16, a16, b16);
    for (int lay = 0; lay < 4; lay++) {
        const f16* wl = Wswz + lay * 98304;
        const float* wdC  = sc + 13568 + lay * 128;
        const float* eb2C = sc + 14592 + lay * 128;
        const float* nb1C = sc + 15104 + lay * 128;
        const float* nb2C = sc + 15616 + lay * 128;
        const float* lngC = sc + 16128 + lay * 128;
        const float* lnbC = sc + 16640 + lay * 128;

        edge_kernel<<<4096, 256, 0, stream>>>(sc, a16, b16, wl + 32768,
                                              eb2C, wdC, m16);
        if (lay < 3) {
            const f16* wlN = Wswz + (lay + 1) * 98304;
            node_mid_kernel<<<256, 64, 0, stream>>>(
                h16, m16, wl + 49152, wl + 81920, nb1C, nb2C, lngC, lnbC,
                wlN, wlN + 16384, sc + 14080 + (lay + 1) * 128, a16, b16);
        } else {
            node_final_kernel<<<256, 64, 0, stream>>>(
                h16, m16, wl + 49152, wl + 81920, nb1C, nb2C, lngC, lnbC,
                sc + 17152, sc + 17536, flag, d_out);
        }
    }
}

// Round 5
// 289.722 us; speedup vs baseline: 1.3066x; 1.0367x over previous
//
#include <hip/hip_runtime.h>

// B=64, N=64, D=128, L=4, T=10. Float tensors may arrive as bf16 OR fp32 —
// detected at runtime (flag in ws), canonicalized before compute.

typedef _Float16 f16;
typedef _Float16 f16x4 __attribute__((ext_vector_type(4)));
typedef _Float16 f16x8 __attribute__((ext_vector_type(8)));
typedef float f32x4 __attribute__((ext_vector_type(4)));

__device__ __forceinline__ float bf2f(unsigned short u) {
    union { unsigned int i; float f; } v; v.i = ((unsigned int)u) << 16; return v.f;
}
__device__ __forceinline__ unsigned short f2bf(float f) {
    union { float f; unsigned int i; } v; v.f = f;
    unsigned int x = v.i;
    return (unsigned short)((x + 0x7fffu + ((x >> 16) & 1u)) >> 16);
}
// fast silu: mul, v_exp_f32, add, v_rcp_f32, mul (2 trans + 3 VALU)
__device__ __forceinline__ float silu_f(float x) {
    float e = __builtin_amdgcn_exp2f(-1.44269504088896f * x);
    return x * __builtin_amdgcn_rcpf(1.0f + e);
}

struct Ptrs { const void* p[14]; };
// p: 0 pos, 1 embed, 2 ew1, 3 eb1, 4 ew2, 5 eb2, 6 nw1, 7 nb1, 8 nw2,
//    9 nb2, 10 lng, 11 lnb, 12 ow, 13 ob

__device__ __forceinline__ float ldf(const void* p, int i, int bf) {
    return bf ? bf2f(((const unsigned short*)p)[i]) : ((const float*)p)[i];
}

// small canon (fp32) offsets: pos 0(12288) embed 12288(1280) wd 13568(512)
// eb1 14080 eb2 14592 nb1 15104 nb2 15616 lng 16128 lnb 16640 (512 each)
// ow 17152(384) ob 17536(3). total 17539.
#define SWZ_TOTAL 393216
#define SMALL_TOTAL 17539

__global__ void detect_kernel(const void* pos, int* flag) {
    int lane = threadIdx.x;   // 64 threads
    const unsigned short* u = (const unsigned short*)pos;
    int ex = (u[lane * 2] >> 7) & 0xFF;
    int ok = (ex >= 110 && ex <= 135) ? 1 : 0;
#pragma unroll
    for (int m = 1; m < 64; m <<= 1) ok += __shfl_xor(ok, m);
    if (lane == 0) *flag = (ok >= 40) ? 1 : 0;   // 1 = bf16, 0 = fp32
}

// Swizzle weights into f16 B-fragment order for mfma_f32_16x16x32_f16:
//   dst[((s*8+c)*64+l)*8 + j] = W[s*32 + (l>>4)*8 + j][c*16 + (l&15)]
// Per-layer: wa@0 wb@16K ew2@32K nw1@48K(32K) nw2@80K; stride 98304.
// Plus small-tensor fp32 canonicalization (tail of the grid).
__global__ __launch_bounds__(256) void prep_kernel(
    Ptrs ptrs, const int* flag, f16* dst, float* sc)
{
    int gid = blockIdx.x * 256 + threadIdx.x;
    int bf = *flag;
    if (gid < SWZ_TOTAL) {
        int lay = gid / 98304;
        int r   = gid % 98304;
        const void* src; int base, rowoff = 0, r2;
        if (r < 49152) {
            int mat = r >> 14; r2 = r & 16383;
            if (mat == 0)      { src = ptrs.p[2]; base = lay * 32896; }
            else if (mat == 1) { src = ptrs.p[2]; base = lay * 32896; rowoff = 128; }
            else               { src = ptrs.p[4]; base = lay * 16384; }
        } else if (r < 81920) {
            r2 = r - 49152; src = ptrs.p[6]; base = lay * 32768;
        } else {
            r2 = r - 81920; src = ptrs.p[8]; base = lay * 16384;
        }
        int s = r2 >> 12, q = r2 & 4095;
        int j = q & 7, l = (q >> 3) & 63, c = q >> 9;
        int row = rowoff + s * 32 + ((l >> 4) << 3) + j;
        int col = (c << 4) + (l & 15);
        dst[gid] = (f16)ldf(src, base + row * 128 + col, bf);
    } else {
        int sid = gid - SWZ_TOTAL;
        if (sid >= SMALL_TOTAL) return;
        const void* src; int i;
        if      (sid < 12288) { src = ptrs.p[0]; i = sid; }
        else if (sid < 13568) { src = ptrs.p[1]; i = sid - 12288; }
        else if (sid < 14080) { int k = sid - 13568;
                                src = ptrs.p[2]; i = (k >> 7) * 32896 + 32768 + (k & 127); }
        else if (sid < 14592) { src = ptrs.p[3];  i = sid - 14080; }
        else if (sid < 15104) { src = ptrs.p[5];  i = sid - 14592; }
        else if (sid < 15616) { src = ptrs.p[7];  i = sid - 15104; }
        else if (sid < 16128) { src = ptrs.p[9];  i = sid - 15616; }
        else if (sid < 16640) { src = ptrs.p[10]; i = sid - 16128; }
        else if (sid < 17152) { src = ptrs.p[11]; i = sid - 16640; }
        else if (sid < 17536) { src = ptrs.p[12]; i = sid - 17152; }
        else                  { src = ptrs.p[13]; i = sid - 17536; }
        sc[sid] = ldf(src, i, bf);
    }
}

// h = embed[an] ; a = h@wa + eb1 ; b = h@wb.  1 wave / 16 rows.
__global__ __launch_bounds__(64) void embed_ab_kernel(
    const int* an, const float* sc, const f16* wa, const f16* wb,
    const float* eb1C, f16* h16, f16* a16, f16* b16)
{
    int lane = threadIdx.x;
    int row0 = blockIdx.x << 4;
    int m_ = lane & 15, q_ = lane >> 4;
    const float* emb = sc + 12288;
    int a = an[row0 + m_];
    a = a < 0 ? 0 : (a > 9 ? 9 : a);
    f16x8 afrag[4];
#pragma unroll
    for (int s = 0; s < 4; s++) {
        f32x4 u0 = *(const f32x4*)(emb + a * 128 + s * 32 + q_ * 8);
        f32x4 u1 = *(const f32x4*)(emb + a * 128 + s * 32 + q_ * 8 + 4);
        f16x8 hv;
#pragma unroll
        for (int e = 0; e < 4; e++) { hv[e] = (f16)u0[e]; hv[e + 4] = (f16)u1[e]; }
        afrag[s] = hv;
        *(f16x8*)(h16 + (row0 + m_) * 128 + s * 32 + q_ * 8) = hv;
    }
#pragma unroll
    for (int mat = 0; mat < 2; mat++) {
        const f16* W = mat ? wb : wa;
        f16* out     = mat ? b16 : a16;
#pragma unroll
        for (int c = 0; c < 8; c++) {
            float init = mat ? 0.0f : eb1C[c * 16 + m_];
            f32x4 acc = { init, init, init, init };
#pragma unroll
            for (int s = 0; s < 4; s++) {
                f16x8 bfr = *(const f16x8*)(W + ((s * 8 + c) * 64 + lane) * 8);
                acc = __builtin_amdgcn_mfma_f32_16x16x32_f16(afrag[s], bfr, acc, 0, 0, 0);
            }
#pragma unroll
            for (int r = 0; r < 4; r++)
                out[(row0 + q_ * 4 + r) * 128 + c * 16 + m_] = (f16)acc[r];
        }
    }
}

// Block per (b,i): m_i = mean_j silu(silu(pre_ij) @ ew2 + eb2)
// Round-3-proven row-split structure; Wlds halved via 2-phase K staging,
// msum overlaid on S after an added barrier. LDS 35 KB -> 4 blocks/CU.
__global__ __launch_bounds__(256) void edge_kernel(
    const float* sc, const f16* a16, const f16* b16,
    const f16* ew2_swz, const float* eb2C, const float* wdC, f16* m_out)
{
    __shared__ f16 Wlds[8192];         // half of swizzled ew2, 16 KB
    __shared__ f16 S[64 * 136];        // silu(pre), stride 136
    __shared__ float a_sh[128];
    __shared__ float wd_sh[128];
    __shared__ float dsq_sh[64];

    int t  = threadIdx.x;
    int ig = blockIdx.x;               // b*64 + i
    int b  = ig >> 6;
    const float* posC = sc;

    // stage half A: fragments s=0,1 == ew2_swz[0..8191]
#pragma unroll
    for (int k = 0; k < 4; k++) {
        int idx = (k * 256 + t) * 8;
        *(f16x8*)(Wlds + idx) = *(const f16x8*)(ew2_swz + idx);
    }
    if (t < 128) a_sh[t] = (float)a16[ig * 128 + t];     // includes eb1
    else         wd_sh[t - 128] = wdC[t - 128];
    if (t < 64) {
        float xi = posC[ig * 3 + 0], yi = posC[ig * 3 + 1], zi = posC[ig * 3 + 2];
        int jg = b * 64 + t;
        float dx = xi - posC[jg * 3 + 0];
        float dy = yi - posC[jg * 3 + 1];
        float dz = zi - posC[jg * 3 + 2];
        dsq_sh[t] = dx * dx + dy * dy + dz * dz;
    }
    __syncthreads();

    // S[j][d] = silu(a_i[d] + b_j[d] + dsq[j]*wd[d])   (round-3 mapping)
    {
        int dj = t >> 5;               // 0..7
        int dbase = (t & 31) * 4;      // 0..124
#pragma unroll
        for (int p = 0; p < 8; p++) {
            int j = p * 8 + dj;
            f16x4 bv = *(const f16x4*)(b16 + (b * 64 + j) * 128 + dbase);
            float ds = dsq_sh[j];
            float p0 = a_sh[dbase + 0] + (float)bv[0] + ds * wd_sh[dbase + 0];
            float p1 = a_sh[dbase + 1] + (float)bv[1] + ds * wd_sh[dbase + 1];
            float p2 = a_sh[dbase + 2] + (float)bv[2] + ds * wd_sh[dbase + 2];
            float p3 = a_sh[dbase + 3] + (float)bv[3] + ds * wd_sh[dbase + 3];
            f16x4 sv = { (f16)silu_f(p0), (f16)silu_f(p1),
                         (f16)silu_f(p2), (f16)silu_f(p3) };
            *(f16x4*)(S + j * 136 + dbase) = sv;
        }
    }
    __syncthreads();

    // GEMM 64x128 @ 128x128: wave w -> S-rows 16w..16w+15, all 128 cols
    int lane = t & 63, w = t >> 6;
    int m_ = lane & 15, q_ = lane >> 4;
    f32x4 acc[8];
#pragma unroll
    for (int c = 0; c < 8; c++) {
        float e = eb2C[c * 16 + m_];
        acc[c] = (f32x4){ e, e, e, e };
    }
    // phase 1: s = 0,1
#pragma unroll
    for (int s = 0; s < 2; s++) {
        f16x8 af = *(const f16x8*)(S + (w * 16 + m_) * 136 + s * 32 + q_ * 8);
#pragma unroll
        for (int c = 0; c < 8; c++) {
            f16x8 bfr = *(const f16x8*)(Wlds + ((s * 8 + c) * 64 + lane) * 8);
            acc[c] = __builtin_amdgcn_mfma_f32_16x16x32_f16(af, bfr, acc[c], 0, 0, 0);
        }
    }
    __syncthreads();                   // all waves done reading half A
    // stage half B: fragments s=2,3 == ew2_swz[8192..16383]
#pragma unroll
    for (int k = 0; k < 4; k++) {
        int idx = (k * 256 + t) * 8;
        *(f16x8*)(Wlds + idx) = *(const f16x8*)(ew2_swz + 8192 + idx);
    }
    __syncthreads();
    // phase 2: s = 2,3 (staged at offset -8192 elements)
#pragma unroll
    for (int s = 2; s < 4; s++) {
        f16x8 af = *(const f16x8*)(S + (w * 16 + m_) * 136 + s * 32 + q_ * 8);
#pragma unroll
        for (int c = 0; c < 8; c++) {
            f16x8 bfr = *(const f16x8*)(Wlds + (((s - 2) * 8 + c) * 64 + lane) * 8);
            acc[c] = __builtin_amdgcn_mfma_f32_16x16x32_f16(af, bfr, acc[c], 0, 0, 0);
        }
    }
    // silu + sum over this wave's 16 rows
    float scv8[8];
#pragma unroll
    for (int c = 0; c < 8; c++) {
        float scv = silu_f(acc[c][0]) + silu_f(acc[c][1]) +
                    silu_f(acc[c][2]) + silu_f(acc[c][3]);
        scv += __shfl_xor(scv, 16);
        scv += __shfl_xor(scv, 32);
        scv8[c] = scv;
    }
    __syncthreads();                   // all waves done reading S
    float* msum = (float*)S;           // overlay: 4 x 128 floats = 2 KB
    if (lane < 16) {
#pragma unroll
        for (int c = 0; c < 8; c++)
            msum[w * 128 + c * 16 + lane] = scv8[c];
    }
    __syncthreads();
    if (t < 128) {
        float mv = (msum[0 * 128 + t] + msum[1 * 128 + t] +
                    msum[2 * 128 + t] + msum[3 * 128 + t]) * (1.0f / 64.0f);
        m_out[ig * 128 + t] = (f16)mv;
    }
}

// Fused node update: u=silu([h|m]@nw1+nb1); x=h+u@nw2+nb2; h'=LN(x)*g+b;
// then next layer's a=h'@wa+eb1, b=h'@wb.  1 wave / 16 rows, no barriers.
__global__ __launch_bounds__(64) void node_mid_kernel(
    const f16* h16, const f16* m16, const f16* nw1s, const f16* nw2s,
    const float* nb1C, const float* nb2C, const float* lngC, const float* lnbC,
    const f16* waN, const f16* wbN, const float* eb1N,
    f16* a16, f16* b16)
{
    __shared__ f16 relay[16 * 136];
    int lane = threadIdx.x;
    int row0 = blockIdx.x << 4;
    int m_ = lane & 15, q_ = lane >> 4;

    f16x8 af[8];
#pragma unroll
    for (int s = 0; s < 4; s++) {
        af[s]     = *(const f16x8*)(h16 + (row0 + m_) * 128 + s * 32 + q_ * 8);
        af[s + 4] = *(const f16x8*)(m16 + (row0 + m_) * 128 + s * 32 + q_ * 8);
    }
    // n1 -> u in relay
#pragma unroll
    for (int c = 0; c < 8; c++) {
        float e = nb1C[c * 16 + m_];
        f32x4 acc = { e, e, e, e };
#pragma unroll
        for (int s = 0; s < 8; s++) {
            f16x8 bfr = *(const f16x8*)(nw1s + ((s * 8 + c) * 64 + lane) * 8);
            acc = __builtin_amdgcn_mfma_f32_16x16x32_f16(af[s], bfr, acc, 0, 0, 0);
        }
#pragma unroll
        for (int r = 0; r < 4; r++)
            relay[(q_ * 4 + r) * 136 + c * 16 + m_] = (f16)silu_f(acc[r]);
    }
    f16x8 uf[4];
#pragma unroll
    for (int s = 0; s < 4; s++)
        uf[s] = *(const f16x8*)(relay + m_ * 136 + s * 32 + q_ * 8);
    // n2 + residual
    float x[8][4];
#pragma unroll
    for (int c = 0; c < 8; c++) {
        float e = nb2C[c * 16 + m_];
        f32x4 acc = { e, e, e, e };
#pragma unroll
        for (int s = 0; s < 4; s++) {
            f16x8 bfr = *(const f16x8*)(nw2s + ((s * 8 + c) * 64 + lane) * 8);
            acc = __builtin_amdgcn_mfma_f32_16x16x32_f16(uf[s], bfr, acc, 0, 0, 0);
        }
#pragma unroll
        for (int r = 0; r < 4; r++)
            x[c][r] = acc[r] + (float)h16[(row0 + q_ * 4 + r) * 128 + c * 16 + m_];
    }
    // LayerNorm + write h' (global + relay for re-layout)
#pragma unroll
    for (int r = 0; r < 4; r++) {
        float s1 = 0.0f, s2 = 0.0f;
#pragma unroll
        for (int c = 0; c < 8; c++) { s1 += x[c][r]; s2 += x[c][r] * x[c][r]; }
#pragma unroll
        for (int msk = 1; msk < 16; msk <<= 1) {
            s1 += __shfl_xor(s1, msk);
            s2 += __shfl_xor(s2, msk);
        }
        float mu  = s1 * (1.0f / 128.0f);
        float var = s2 * (1.0f / 128.0f) - mu * mu;
        float rs  = rsqrtf(var + 1e-5f);
        int row = row0 + q_ * 4 + r;
#pragma unroll
        for (int c = 0; c < 8; c++) {
            int col = c * 16 + m_;
            float y = (x[c][r] - mu) * rs * lngC[col] + lnbC[col];
            ((f16*)h16)[row * 128 + col] = (f16)y;
            relay[(q_ * 4 + r) * 136 + col] = (f16)y;
        }
    }
    f16x8 hf[4];
#pragma unroll
    for (int s = 0; s < 4; s++)
        hf[s] = *(const f16x8*)(relay + m_ * 136 + s * 32 + q_ * 8);
    // next layer a,b
#pragma unroll
    for (int mat = 0; mat < 2; mat++) {
        const f16* W = mat ? wbN : waN;
        f16* out     = mat ? b16 : a16;
#pragma unroll
        for (int c = 0; c < 8; c++) {
            float init = mat ? 0.0f : eb1N[c * 16 + m_];
            f32x4 acc = { init, init, init, init };
#pragma unroll
            for (int s = 0; s < 4; s++) {
                f16x8 bfr = *(const f16x8*)(W + ((s * 8 + c) * 64 + lane) * 8);
                acc = __builtin_amdgcn_mfma_f32_16x16x32_f16(hf[s], bfr, acc, 0, 0, 0);
            }
#pragma unroll
            for (int r = 0; r < 4; r++)
                out[(row0 + q_ * 4 + r) * 128 + c * 16 + m_] = (f16)acc[r];
        }
    }
}

// Last layer: node update then out = h'@ow + ob
__global__ __launch_bounds__(64) void node_final_kernel(
    const f16* h16, const f16* m16, const f16* nw1s, const f16* nw2s,
    const float* nb1C, const float* nb2C, const float* lngC, const float* lnbC,
    const float* owC, const float* obC, const int* flag, void* out)
{
    __shared__ f16 relay[16 * 136];
    int lane = threadIdx.x;
    int row0 = blockIdx.x << 4;
    int m_ = lane & 15, q_ = lane >> 4;

    f16x8 af[8];
#pragma unroll
    for (int s = 0; s < 4; s++) {
        af[s]     = *(const f16x8*)(h16 + (row0 + m_) * 128 + s * 32 + q_ * 8);
        af[s + 4] = *(const f16x8*)(m16 + (row0 + m_) * 128 + s * 32 + q_ * 8);
    }
#pragma unroll
    for (int c = 0; c < 8; c++) {
        float e = nb1C[c * 16 + m_];
        f32x4 acc = { e, e, e, e };
#pragma unroll
        for (int s = 0; s < 8; s++) {
            f16x8 bfr = *(const f16x8*)(nw1s + ((s * 8 + c) * 64 + lane) * 8);
            acc = __builtin_amdgcn_mfma_f32_16x16x32_f16(af[s], bfr, acc, 0, 0, 0);
        }
#pragma unroll
        for (int r = 0; r < 4; r++)
            relay[(q_ * 4 + r) * 136 + c * 16 + m_] = (f16)silu_f(acc[r]);
    }
    f16x8 uf[4];
#pragma unroll
    for (int s = 0; s < 4; s++)
        uf[s] = *(const f16x8*)(relay + m_ * 136 + s * 32 + q_ * 8);
    float x[8][4];
#pragma unroll
    for (int c = 0; c < 8; c++) {
        float e = nb2C[c * 16 + m_];
        f32x4 acc = { e, e, e, e };
#pragma unroll
        for (int s = 0; s < 4; s++) {
            f16x8 bfr = *(const f16x8*)(nw2s + ((s * 8 + c) * 64 + lane) * 8);
            acc = __builtin_amdgcn_mfma_f32_16x16x32_f16(uf[s], bfr, acc, 0, 0, 0);
        }
#pragma unroll
        for (int r = 0; r < 4; r++)
            x[c][r] = acc[r] + (float)h16[(row0 + q_ * 4 + r) * 128 + c * 16 + m_];
    }
    int bf = *flag;
#pragma unroll
    for (int r = 0; r < 4; r++) {
        float s1 = 0.0f, s2 = 0.0f;
#pragma unroll
        for (int c = 0; c < 8; c++) { s1 += x[c][r]; s2 += x[c][r] * x[c][r]; }
#pragma unroll
        for (int msk = 1; msk < 16; msk <<= 1) {
            s1 += __shfl_xor(s1, msk);
            s2 += __shfl_xor(s2, msk);
        }
        float mu  = s1 * (1.0f / 128.0f);
        float var = s2 * (1.0f / 128.0f) - mu * mu;
        float rs  = rsqrtf(var + 1e-5f);
        float p0 = 0.0f, p1 = 0.0f, p2 = 0.0f;
#pragma unroll
        for (int c = 0; c < 8; c++) {
            int col = c * 16 + m_;
            float y = (x[c][r] - mu) * rs * lngC[col] + lnbC[col];
            p0 += y * owC[col * 3 + 0];
            p1 += y * owC[col * 3 + 1];
            p2 += y * owC[col * 3 + 2];
        }
#pragma unroll
        for (int msk = 1; msk < 16; msk <<= 1) {
            p0 += __shfl_xor(p0, msk);
            p1 += __shfl_xor(p1, msk);
            p2 += __shfl_xor(p2, msk);
        }
        if (m_ == 0) {
            int row = row0 + q_ * 4 + r;
            p0 += obC[0]; p1 += obC[1]; p2 += obC[2];
            if (bf) {
                unsigned short* o = (unsigned short*)out;
                o[row * 3 + 0] = f2bf(p0);
                o[row * 3 + 1] = f2bf(p1);
                o[row * 3 + 2] = f2bf(p2);
            } else {
                float* o = (float*)out;
                o[row * 3 + 0] = p0;
                o[row * 3 + 1] = p1;
                o[row * 3 + 2] = p2;
            }
        }
    }
}

extern "C" void kernel_launch(void* const* d_in, const int* in_sizes, int n_in,
                              void* d_out, int out_size, void* d_ws, size_t ws_size,
                              hipStream_t stream)
{
    const int* an = (const int*)d_in[1];

    char* ws = (char*)d_ws;
    int*   flag = (int*)ws;
    float* sc   = (float*)(ws + 1024);              // 70 KB
    f16*   Wswz = (f16*)(ws + (128u << 10));        // 768 KB
    f16*   h16  = (f16*)(ws + (1u << 20));          // 1 MB
    f16*   a16  = (f16*)(ws + (2u << 20));
    f16*   b16  = (f16*)(ws + (3u << 20));
    f16*   m16  = (f16*)(ws + (4u << 20));          // total 5 MB

    Ptrs ptrs;
    const int src_idx[14] = {0, 2, 3, 4, 5, 6, 7, 8, 9, 10, 11, 12, 13, 14};
    for (int k = 0; k < 14; k++) ptrs.p[k] = d_in[src_idx[k]];

    detect_kernel<<<1, 64, 0, stream>>>(d_in[0], flag);
    prep_kernel<<<1605, 256, 0, stream>>>(ptrs, flag, Wswz, sc);
    embed_ab_kernel<<<256, 64, 0, stream>>>(an, sc, Wswz, Wswz + 16384,
                                            sc + 14080, h16, a16, b16);
    for (int lay = 0; lay < 4; lay++) {
        const f16* wl = Wswz + lay * 98304;
        const float* wdC  = sc + 13568 + lay * 128;
        const float* eb2C = sc + 14592 + lay * 128;
        const float* nb1C = sc + 15104 + lay * 128;
        const float* nb2C = sc + 15616 + lay * 128;
        const float* lngC = sc + 16128 + lay * 128;
        const float* lnbC = sc + 16640 + lay * 128;

        edge_kernel<<<4096, 256, 0, stream>>>(sc, a16, b16, wl + 32768,
                                              eb2C, wdC, m16);
        if (lay < 3) {
            const f16* wlN = Wswz + (lay + 1) * 98304;
            node_mid_kernel<<<256, 64, 0, stream>>>(
                h16, m16, wl + 49152, wl + 81920, nb1C, nb2C, lngC, lnbC,
                wlN, wlN + 16384, sc + 14080 + (lay + 1) * 128, a16, b16);
        } else {
            node_final_kernel<<<256, 64, 0, stream>>>(
                h16, m16, wl + 49152, wl + 81920, nb1C, nb2C, lngC, lnbC,
                sc + 17152, sc + 17536, flag, d_out);
        }
    }
}

// Round 6
// 227.408 us; speedup vs baseline: 1.6646x; 1.2740x over previous
//
#include <hip/hip_runtime.h>

// B=64, N=64, D=128, L=4, T=10. Float tensors may arrive as bf16 OR fp32 —
// detected per-block (wave-0 ballot on positions' u16 exponent pattern).

typedef _Float16 f16;
typedef _Float16 f16x4 __attribute__((ext_vector_type(4)));
typedef _Float16 f16x8 __attribute__((ext_vector_type(8)));
typedef float f32x4 __attribute__((ext_vector_type(4)));

__device__ __forceinline__ float bf2f(unsigned short u) {
    union { unsigned int i; float f; } v; v.i = ((unsigned int)u) << 16; return v.f;
}
__device__ __forceinline__ unsigned short f2bf(float f) {
    union { float f; unsigned int i; } v; v.f = f;
    unsigned int x = v.i;
    return (unsigned short)((x + 0x7fffu + ((x >> 16) & 1u)) >> 16);
}
// fast silu: mul, v_exp_f32, add, v_rcp_f32, mul (2 trans + 3 VALU)
__device__ __forceinline__ float silu_f(float x) {
    float e = __builtin_amdgcn_exp2f(-1.44269504088896f * x);
    return x * __builtin_amdgcn_rcpf(1.0f + e);
}

struct Ptrs { const void* p[14]; };
// p: 0 pos, 1 embed, 2 ew1, 3 eb1, 4 ew2, 5 eb2, 6 nw1, 7 nb1, 8 nw2,
//    9 nb2, 10 lng, 11 lnb, 12 ow, 13 ob

__device__ __forceinline__ float ldf(const void* p, int i, int bf) {
    return bf ? bf2f(((const unsigned short*)p)[i]) : ((const float*)p)[i];
}

// small canon (fp32) offsets: pos 0(12288) embed 12288(1280) wd 13568(512)
// eb1 14080 eb2 14592 nb1 15104 nb2 15616 lng 16128 lnb 16640 (512 each)
// ow 17152(384) ob 17536(3). total 17539.
#define SWZ_TOTAL 393216
#define SMALL_TOTAL 17539

// Swizzle weights into f16 B-fragment order for mfma_f32_16x16x32_f16:
//   dst[((s*8+c)*64+l)*8 + j] = W[s*32 + (l>>4)*8 + j][c*16 + (l&15)]
// Per-layer: wa@0 wb@16K ew2@32K nw1@48K(32K) nw2@80K; stride 98304.
// Plus small-tensor fp32 canonicalization. dtype detected per-block (wave 0).
__global__ __launch_bounds__(256) void prep_kernel(
    Ptrs ptrs, f16* dst, float* sc)
{
    __shared__ int flgsh;
    int t = threadIdx.x;
    if (t < 64) {
        int ex = (((const unsigned short*)ptrs.p[0])[t * 2] >> 7) & 0xFF;
        unsigned long long m = __ballot(ex >= 110 && ex <= 135);
        if (t == 0) flgsh = (__popcll(m) >= 40) ? 1 : 0;
    }
    __syncthreads();
    int bf = flgsh;

    int gid = blockIdx.x * 256 + t;
    if (gid < SWZ_TOTAL) {
        int lay = gid / 98304;
        int r   = gid % 98304;
        const void* src; int base, rowoff = 0, r2;
        if (r < 49152) {
            int mat = r >> 14; r2 = r & 16383;
            if (mat == 0)      { src = ptrs.p[2]; base = lay * 32896; }
            else if (mat == 1) { src = ptrs.p[2]; base = lay * 32896; rowoff = 128; }
            else               { src = ptrs.p[4]; base = lay * 16384; }
        } else if (r < 81920) {
            r2 = r - 49152; src = ptrs.p[6]; base = lay * 32768;
        } else {
            r2 = r - 81920; src = ptrs.p[8]; base = lay * 16384;
        }
        int s = r2 >> 12, q = r2 & 4095;
        int j = q & 7, l = (q >> 3) & 63, c = q >> 9;
        int row = rowoff + s * 32 + ((l >> 4) << 3) + j;
        int col = (c << 4) + (l & 15);
        dst[gid] = (f16)ldf(src, base + row * 128 + col, bf);
    } else {
        int sid = gid - SWZ_TOTAL;
        if (sid >= SMALL_TOTAL) return;
        const void* src; int i;
        if      (sid < 12288) { src = ptrs.p[0]; i = sid; }
        else if (sid < 13568) { src = ptrs.p[1]; i = sid - 12288; }
        else if (sid < 14080) { int k = sid - 13568;
                                src = ptrs.p[2]; i = (k >> 7) * 32896 + 32768 + (k & 127); }
        else if (sid < 14592) { src = ptrs.p[3];  i = sid - 14080; }
        else if (sid < 15104) { src = ptrs.p[5];  i = sid - 14592; }
        else if (sid < 15616) { src = ptrs.p[7];  i = sid - 15104; }
        else if (sid < 16128) { src = ptrs.p[9];  i = sid - 15616; }
        else if (sid < 16640) { src = ptrs.p[10]; i = sid - 16128; }
        else if (sid < 17152) { src = ptrs.p[11]; i = sid - 16640; }
        else if (sid < 17536) { src = ptrs.p[12]; i = sid - 17152; }
        else                  { src = ptrs.p[13]; i = sid - 17536; }
        sc[sid] = ldf(src, i, bf);
    }
}

// h = embed[an]; a = h@wa + eb1; b = h@wb.
// 256 threads / 16 rows: wave w computes output cols c = 2w, 2w+1 (both mats).
__global__ __launch_bounds__(256) void embed_ab_kernel(
    const int* an, const float* sc, const f16* wa, const f16* wb,
    const float* eb1C, f16* h16, f16* a16, f16* b16)
{
    int t = threadIdx.x;
    int w = t >> 6, lane = t & 63;
    int row0 = blockIdx.x << 4;
    int m_ = lane & 15, q_ = lane >> 4;
    const float* emb = sc + 12288;
    int a = an[row0 + m_];
    a = a < 0 ? 0 : (a > 9 ? 9 : a);
    f16x8 afrag[4];
#pragma unroll
    for (int s = 0; s < 4; s++) {
        f32x4 u0 = *(const f32x4*)(emb + a * 128 + s * 32 + q_ * 8);
        f32x4 u1 = *(const f32x4*)(emb + a * 128 + s * 32 + q_ * 8 + 4);
        f16x8 hv;
#pragma unroll
        for (int e = 0; e < 4; e++) { hv[e] = (f16)u0[e]; hv[e + 4] = (f16)u1[e]; }
        afrag[s] = hv;
        if (w == 0)
            *(f16x8*)(h16 + (row0 + m_) * 128 + s * 32 + q_ * 8) = hv;
    }
#pragma unroll
    for (int mat = 0; mat < 2; mat++) {
        const f16* W = mat ? wb : wa;
        f16* out     = mat ? b16 : a16;
#pragma unroll
        for (int cc = 0; cc < 2; cc++) {
            int c = 2 * w + cc;
            float init = mat ? 0.0f : eb1C[c * 16 + m_];
            f32x4 acc = { init, init, init, init };
#pragma unroll
            for (int s = 0; s < 4; s++) {
                f16x8 bfr = *(const f16x8*)(W + ((s * 8 + c) * 64 + lane) * 8);
                acc = __builtin_amdgcn_mfma_f32_16x16x32_f16(afrag[s], bfr, acc, 0, 0, 0);
            }
#pragma unroll
            for (int r = 0; r < 4; r++)
                out[(row0 + q_ * 4 + r) * 128 + c * 16 + m_] = (f16)acc[r];
        }
    }
}

// Block per (b,i): m_i = mean_j silu(silu(pre_ij) @ ew2 + eb2)
// Proven r5 structure: 2-phase K staging of ew2, msum overlaid on S. 35 KB LDS.
__global__ __launch_bounds__(256) void edge_kernel(
    const float* sc, const f16* a16, const f16* b16,
    const f16* ew2_swz, const float* eb2C, const float* wdC, f16* m_out)
{
    __shared__ f16 Wlds[8192];         // half of swizzled ew2, 16 KB
    __shared__ f16 S[64 * 136];        // silu(pre), stride 136
    __shared__ float a_sh[128];
    __shared__ float wd_sh[128];
    __shared__ float dsq_sh[64];

    int t  = threadIdx.x;
    int ig = blockIdx.x;               // b*64 + i
    int b  = ig >> 6;
    const float* posC = sc;

    // stage half A: fragments s=0,1 == ew2_swz[0..8191]
#pragma unroll
    for (int k = 0; k < 4; k++) {
        int idx = (k * 256 + t) * 8;
        *(f16x8*)(Wlds + idx) = *(const f16x8*)(ew2_swz + idx);
    }
    if (t < 128) a_sh[t] = (float)a16[ig * 128 + t];     // includes eb1
    else         wd_sh[t - 128] = wdC[t - 128];
    if (t < 64) {
        float xi = posC[ig * 3 + 0], yi = posC[ig * 3 + 1], zi = posC[ig * 3 + 2];
        int jg = b * 64 + t;
        float dx = xi - posC[jg * 3 + 0];
        float dy = yi - posC[jg * 3 + 1];
        float dz = zi - posC[jg * 3 + 2];
        dsq_sh[t] = dx * dx + dy * dy + dz * dz;
    }
    __syncthreads();

    // S[j][d] = silu(a_i[d] + b_j[d] + dsq[j]*wd[d])
    {
        int dj = t >> 5;               // 0..7
        int dbase = (t & 31) * 4;      // 0..124
#pragma unroll
        for (int p = 0; p < 8; p++) {
            int j = p * 8 + dj;
            f16x4 bv = *(const f16x4*)(b16 + (b * 64 + j) * 128 + dbase);
            float ds = dsq_sh[j];
            float p0 = a_sh[dbase + 0] + (float)bv[0] + ds * wd_sh[dbase + 0];
            float p1 = a_sh[dbase + 1] + (float)bv[1] + ds * wd_sh[dbase + 1];
            float p2 = a_sh[dbase + 2] + (float)bv[2] + ds * wd_sh[dbase + 2];
            float p3 = a_sh[dbase + 3] + (float)bv[3] + ds * wd_sh[dbase + 3];
            f16x4 sv = { (f16)silu_f(p0), (f16)silu_f(p1),
                         (f16)silu_f(p2), (f16)silu_f(p3) };
            *(f16x4*)(S + j * 136 + dbase) = sv;
        }
    }
    __syncthreads();

    // GEMM 64x128 @ 128x128: wave w -> S-rows 16w..16w+15, all 128 cols
    int lane = t & 63, w = t >> 6;
    int m_ = lane & 15, q_ = lane >> 4;
    f32x4 acc[8];
#pragma unroll
    for (int c = 0; c < 8; c++) {
        float e = eb2C[c * 16 + m_];
        acc[c] = (f32x4){ e, e, e, e };
    }
    // phase 1: s = 0,1
#pragma unroll
    for (int s = 0; s < 2; s++) {
        f16x8 af = *(const f16x8*)(S + (w * 16 + m_) * 136 + s * 32 + q_ * 8);
#pragma unroll
        for (int c = 0; c < 8; c++) {
            f16x8 bfr = *(const f16x8*)(Wlds + ((s * 8 + c) * 64 + lane) * 8);
            acc[c] = __builtin_amdgcn_mfma_f32_16x16x32_f16(af, bfr, acc[c], 0, 0, 0);
        }
    }
    __syncthreads();                   // all waves done reading half A
    // stage half B: fragments s=2,3 == ew2_swz[8192..16383]
#pragma unroll
    for (int k = 0; k < 4; k++) {
        int idx = (k * 256 + t) * 8;
        *(f16x8*)(Wlds + idx) = *(const f16x8*)(ew2_swz + 8192 + idx);
    }
    __syncthreads();
    // phase 2: s = 2,3 (staged at offset -8192 elements)
#pragma unroll
    for (int s = 2; s < 4; s++) {
        f16x8 af = *(const f16x8*)(S + (w * 16 + m_) * 136 + s * 32 + q_ * 8);
#pragma unroll
        for (int c = 0; c < 8; c++) {
            f16x8 bfr = *(const f16x8*)(Wlds + (((s - 2) * 8 + c) * 64 + lane) * 8);
            acc[c] = __builtin_amdgcn_mfma_f32_16x16x32_f16(af, bfr, acc[c], 0, 0, 0);
        }
    }
    // silu + sum over this wave's 16 rows
    float scv8[8];
#pragma unroll
    for (int c = 0; c < 8; c++) {
        float scv = silu_f(acc[c][0]) + silu_f(acc[c][1]) +
                    silu_f(acc[c][2]) + silu_f(acc[c][3]);
        scv += __shfl_xor(scv, 16);
        scv += __shfl_xor(scv, 32);
        scv8[c] = scv;
    }
    __syncthreads();                   // all waves done reading S
    float* msum = (float*)S;           // overlay: 4 x 128 floats = 2 KB
    if (lane < 16) {
#pragma unroll
        for (int c = 0; c < 8; c++)
            msum[w * 128 + c * 16 + lane] = scv8[c];
    }
    __syncthreads();
    if (t < 128) {
        float mv = (msum[0 * 128 + t] + msum[1 * 128 + t] +
                    msum[2 * 128 + t] + msum[3 * 128 + t]) * (1.0f / 64.0f);
        m_out[ig * 128 + t] = (f16)mv;
    }
}

// Fused node update, 256 threads / 16 rows, column-split across 4 waves:
// u=silu([h|m]@nw1+nb1); x=h+u@nw2+nb2; h'=LN(x)*g+b; next a,b.
__global__ __launch_bounds__(256) void node_mid_kernel(
    const f16* h16, const f16* m16, const f16* nw1s, const f16* nw2s,
    const float* nb1C, const float* nb2C, const float* lngC, const float* lnbC,
    const f16* waN, const f16* wbN, const float* eb1N,
    f16* a16, f16* b16)
{
    __shared__ f16 relay[16 * 136];
    __shared__ float s1sh[4][16], s2sh[4][16];
    int t = threadIdx.x;
    int w = t >> 6, lane = t & 63;
    int row0 = blockIdx.x << 4;
    int m_ = lane & 15, q_ = lane >> 4;

    f16x8 af[8];
#pragma unroll
    for (int s = 0; s < 4; s++) {
        af[s]     = *(const f16x8*)(h16 + (row0 + m_) * 128 + s * 32 + q_ * 8);
        af[s + 4] = *(const f16x8*)(m16 + (row0 + m_) * 128 + s * 32 + q_ * 8);
    }
    // n1: wave w -> cols c = 2w, 2w+1
#pragma unroll
    for (int cc = 0; cc < 2; cc++) {
        int c = 2 * w + cc;
        float e = nb1C[c * 16 + m_];
        f32x4 acc = { e, e, e, e };
#pragma unroll
        for (int s = 0; s < 8; s++) {
            f16x8 bfr = *(const f16x8*)(nw1s + ((s * 8 + c) * 64 + lane) * 8);
            acc = __builtin_amdgcn_mfma_f32_16x16x32_f16(af[s], bfr, acc, 0, 0, 0);
        }
#pragma unroll
        for (int r = 0; r < 4; r++)
            relay[(q_ * 4 + r) * 136 + c * 16 + m_] = (f16)silu_f(acc[r]);
    }
    __syncthreads();
    f16x8 uf[4];
#pragma unroll
    for (int s = 0; s < 4; s++)
        uf[s] = *(const f16x8*)(relay + m_ * 136 + s * 32 + q_ * 8);
    // n2 + residual (this wave's 2 cols only)
    float x[2][4];
#pragma unroll
    for (int cc = 0; cc < 2; cc++) {
        int c = 2 * w + cc;
        float e = nb2C[c * 16 + m_];
        f32x4 acc = { e, e, e, e };
#pragma unroll
        for (int s = 0; s < 4; s++) {
            f16x8 bfr = *(const f16x8*)(nw2s + ((s * 8 + c) * 64 + lane) * 8);
            acc = __builtin_amdgcn_mfma_f32_16x16x32_f16(uf[s], bfr, acc, 0, 0, 0);
        }
#pragma unroll
        for (int r = 0; r < 4; r++)
            x[cc][r] = acc[r] + (float)h16[(row0 + q_ * 4 + r) * 128 + c * 16 + m_];
    }
    // LN: per-row partials over this wave's 2 cols, reduce over m_ then waves
    float s1p[4], s2p[4];
#pragma unroll
    for (int r = 0; r < 4; r++) {
        s1p[r] = x[0][r] + x[1][r];
        s2p[r] = x[0][r] * x[0][r] + x[1][r] * x[1][r];
    }
#pragma unroll
    for (int msk = 1; msk < 16; msk <<= 1)
#pragma unroll
        for (int r = 0; r < 4; r++) {
            s1p[r] += __shfl_xor(s1p[r], msk);
            s2p[r] += __shfl_xor(s2p[r], msk);
        }
    if (m_ == 0)
#pragma unroll
        for (int r = 0; r < 4; r++) {
            s1sh[w][q_ * 4 + r] = s1p[r];
            s2sh[w][q_ * 4 + r] = s2p[r];
        }
    __syncthreads();
    float mu[4], rs[4];
#pragma unroll
    for (int r = 0; r < 4; r++) {
        int row = q_ * 4 + r;
        float S1 = s1sh[0][row] + s1sh[1][row] + s1sh[2][row] + s1sh[3][row];
        float S2 = s2sh[0][row] + s2sh[1][row] + s2sh[2][row] + s2sh[3][row];
        mu[r] = S1 * (1.0f / 128.0f);
        float var = S2 * (1.0f / 128.0f) - mu[r] * mu[r];
        rs[r] = rsqrtf(var + 1e-5f);
    }
#pragma unroll
    for (int cc = 0; cc < 2; cc++) {
        int c = 2 * w + cc;
#pragma unroll
        for (int r = 0; r < 4; r++) {
            int col = c * 16 + m_;
            int row = row0 + q_ * 4 + r;
            float y = (x[cc][r] - mu[r]) * rs[r] * lngC[col] + lnbC[col];
            ((f16*)h16)[row * 128 + col] = (f16)y;
            relay[(q_ * 4 + r) * 136 + col] = (f16)y;
        }
    }
    __syncthreads();
    f16x8 hf[4];
#pragma unroll
    for (int s = 0; s < 4; s++)
        hf[s] = *(const f16x8*)(relay + m_ * 136 + s * 32 + q_ * 8);
    // next layer a,b (this wave's 2 cols)
#pragma unroll
    for (int mat = 0; mat < 2; mat++) {
        const f16* W = mat ? wbN : waN;
        f16* out     = mat ? b16 : a16;
#pragma unroll
        for (int cc = 0; cc < 2; cc++) {
            int c = 2 * w + cc;
            float init = mat ? 0.0f : eb1N[c * 16 + m_];
            f32x4 acc = { init, init, init, init };
#pragma unroll
            for (int s = 0; s < 4; s++) {
                f16x8 bfr = *(const f16x8*)(W + ((s * 8 + c) * 64 + lane) * 8);
                acc = __builtin_amdgcn_mfma_f32_16x16x32_f16(hf[s], bfr, acc, 0, 0, 0);
            }
#pragma unroll
            for (int r = 0; r < 4; r++)
                out[(row0 + q_ * 4 + r) * 128 + c * 16 + m_] = (f16)acc[r];
        }
    }
}

// Last layer: node update then out = h'@ow + ob. Same 256-thread split.
__global__ __launch_bounds__(256) void node_final_kernel(
    const void* pos_raw, const f16* h16, const f16* m16,
    const f16* nw1s, const f16* nw2s,
    const float* nb1C, const float* nb2C, const float* lngC, const float* lnbC,
    const float* owC, const float* obC, void* out)
{
    __shared__ f16 relay[16 * 136];
    __shared__ float s1sh[4][16], s2sh[4][16];
    __shared__ float psh[4][16][3];
    __shared__ int flgsh;
    int t = threadIdx.x;
    int w = t >> 6, lane = t & 63;
    int row0 = blockIdx.x << 4;
    int m_ = lane & 15, q_ = lane >> 4;

    if (t < 64) {
        int ex = (((const unsigned short*)pos_raw)[t * 2] >> 7) & 0xFF;
        unsigned long long mk = __ballot(ex >= 110 && ex <= 135);
        if (t == 0) flgsh = (__popcll(mk) >= 40) ? 1 : 0;
    }

    f16x8 af[8];
#pragma unroll
    for (int s = 0; s < 4; s++) {
        af[s]     = *(const f16x8*)(h16 + (row0 + m_) * 128 + s * 32 + q_ * 8);
        af[s + 4] = *(const f16x8*)(m16 + (row0 + m_) * 128 + s * 32 + q_ * 8);
    }
#pragma unroll
    for (int cc = 0; cc < 2; cc++) {
        int c = 2 * w + cc;
        float e = nb1C[c * 16 + m_];
        f32x4 acc = { e, e, e, e };
#pragma unroll
        for (int s = 0; s < 8; s++) {
            f16x8 bfr = *(const f16x8*)(nw1s + ((s * 8 + c) * 64 + lane) * 8);
            acc = __builtin_amdgcn_mfma_f32_16x16x32_f16(af[s], bfr, acc, 0, 0, 0);
        }
#pragma unroll
        for (int r = 0; r < 4; r++)
            relay[(q_ * 4 + r) * 136 + c * 16 + m_] = (f16)silu_f(acc[r]);
    }
    __syncthreads();
    f16x8 uf[4];
#pragma unroll
    for (int s = 0; s < 4; s++)
        uf[s] = *(const f16x8*)(relay + m_ * 136 + s * 32 + q_ * 8);
    float x[2][4];
#pragma unroll
    for (int cc = 0; cc < 2; cc++) {
        int c = 2 * w + cc;
        float e = nb2C[c * 16 + m_];
        f32x4 acc = { e, e, e, e };
#pragma unroll
        for (int s = 0; s < 4; s++) {
            f16x8 bfr = *(const f16x8*)(nw2s + ((s * 8 + c) * 64 + lane) * 8);
            acc = __builtin_amdgcn_mfma_f32_16x16x32_f16(uf[s], bfr, acc, 0, 0, 0);
        }
#pragma unroll
        for (int r = 0; r < 4; r++)
            x[cc][r] = acc[r] + (float)h16[(row0 + q_ * 4 + r) * 128 + c * 16 + m_];
    }
    float s1p[4], s2p[4];
#pragma unroll
    for (int r = 0; r < 4; r++) {
        s1p[r] = x[0][r] + x[1][r];
        s2p[r] = x[0][r] * x[0][r] + x[1][r] * x[1][r];
    }
#pragma unroll
    for (int msk = 1; msk < 16; msk <<= 1)
#pragma unroll
        for (int r = 0; r < 4; r++) {
            s1p[r] += __shfl_xor(s1p[r], msk);
            s2p[r] += __shfl_xor(s2p[r], msk);
        }
    if (m_ == 0)
#pragma unroll
        for (int r = 0; r < 4; r++) {
            s1sh[w][q_ * 4 + r] = s1p[r];
            s2sh[w][q_ * 4 + r] = s2p[r];
        }
    __syncthreads();
    // out projection: per-row partials over this wave's 2 cols
    float p[3][4];
#pragma unroll
    for (int r = 0; r < 4; r++) {
        int row = q_ * 4 + r;
        float S1 = s1sh[0][row] + s1sh[1][row] + s1sh[2][row] + s1sh[3][row];
        float S2 = s2sh[0][row] + s2sh[1][row] + s2sh[2][row] + s2sh[3][row];
        float mu = S1 * (1.0f / 128.0f);
        float var = S2 * (1.0f / 128.0f) - mu * mu;
        float rs = rsqrtf(var + 1e-5f);
        float p0 = 0.0f, p1 = 0.0f, p2 = 0.0f;
#pragma unroll
        for (int cc = 0; cc < 2; cc++) {
            int col = (2 * w + cc) * 16 + m_;
            float y = (x[cc][r] - mu) * rs * lngC[col] + lnbC[col];
            p0 += y * owC[col * 3 + 0];
            p1 += y * owC[col * 3 + 1];
            p2 += y * owC[col * 3 + 2];
        }
        p[0][r] = p0; p[1][r] = p1; p[2][r] = p2;
    }
#pragma unroll
    for (int msk = 1; msk < 16; msk <<= 1)
#pragma unroll
        for (int k = 0; k < 3; k++)
#pragma unroll
            for (int r = 0; r < 4; r++)
                p[k][r] += __shfl_xor(p[k][r], msk);
    if (m_ == 0)
#pragma unroll
        for (int r = 0; r < 4; r++)
#pragma unroll
            for (int k = 0; k < 3; k++)
                psh[w][q_ * 4 + r][k] = p[k][r];
    __syncthreads();
    if (t < 16) {
        int row = row0 + t;
        int bf = flgsh;
#pragma unroll
        for (int k = 0; k < 3; k++) {
            float v = psh[0][t][k] + psh[1][t][k] + psh[2][t][k] + psh[3][t][k]
                      + obC[k];
            if (bf) ((unsigned short*)out)[row * 3 + k] = f2bf(v);
            else    ((float*)out)[row * 3 + k] = v;
        }
    }
}

extern "C" void kernel_launch(void* const* d_in, const int* in_sizes, int n_in,
                              void* d_out, int out_size, void* d_ws, size_t ws_size,
                              hipStream_t stream)
{
    const int* an = (const int*)d_in[1];

    char* ws = (char*)d_ws;
    float* sc   = (float*)(ws + 1024);              // 70 KB
    f16*   Wswz = (f16*)(ws + (128u << 10));        // 768 KB
    f16*   h16  = (f16*)(ws + (1u << 20));          // 1 MB
    f16*   a16  = (f16*)(ws + (2u << 20));
    f16*   b16  = (f16*)(ws + (3u << 20));
    f16*   m16  = (f16*)(ws + (4u << 20));          // total 5 MB

    Ptrs ptrs;
    const int src_idx[14] = {0, 2, 3, 4, 5, 6, 7, 8, 9, 10, 11, 12, 13, 14};
    for (int k = 0; k < 14; k++) ptrs.p[k] = d_in[src_idx[k]];

    prep_kernel<<<1605, 256, 0, stream>>>(ptrs, Wswz, sc);
    embed_ab_kernel<<<256, 256, 0, stream>>>(an, sc, Wswz, Wswz + 16384,
                                             sc + 14080, h16, a16, b16);
    for (int lay = 0; lay < 4; lay++) {
        const f16* wl = Wswz + lay * 98304;
        const float* wdC  = sc + 13568 + lay * 128;
        const float* eb2C = sc + 14592 + lay * 128;
        const float* nb1C = sc + 15104 + lay * 128;
        const float* nb2C = sc + 15616 + lay * 128;
        const float* lngC = sc + 16128 + lay * 128;
        const float* lnbC = sc + 16640 + lay * 128;

        edge_kernel<<<4096, 256, 0, stream>>>(sc, a16, b16, wl + 32768,
                                              eb2C, wdC, m16);
        if (lay < 3) {
            const f16* wlN = Wswz + (lay + 1) * 98304;
            node_mid_kernel<<<256, 256, 0, stream>>>(
                h16, m16, wl + 49152, wl + 81920, nb1C, nb2C, lngC, lnbC,
                wlN, wlN + 16384, sc + 14080 + (lay + 1) * 128, a16, b16);
        } else {
            node_final_kernel<<<256, 256, 0, stream>>>(
                d_in[0], h16, m16, wl + 49152, wl + 81920,
                nb1C, nb2C, lngC, lnbC,
                sc + 17152, sc + 17536, d_out);
        }
    }
}

// Round 7
// 220.538 us; speedup vs baseline: 1.7165x; 1.0312x over previous
//
#include <hip/hip_runtime.h>
#include <hip/hip_fp16.h>

// B=64, N=64, D=128, L=4, T=10. Float tensors may arrive as bf16 OR fp32 —
// detected per-block (wave-0 ballot on positions' u16 exponent pattern).

typedef _Float16 f16;
typedef _Float16 f16x4 __attribute__((ext_vector_type(4)));
typedef _Float16 f16x8 __attribute__((ext_vector_type(8)));
typedef float f32x4 __attribute__((ext_vector_type(4)));

union H2x4 { f16x8 v; __half2 h[4]; };

__device__ __forceinline__ float bf2f(unsigned short u) {
    union { unsigned int i; float f; } v; v.i = ((unsigned int)u) << 16; return v.f;
}
__device__ __forceinline__ unsigned short f2bf(float f) {
    union { float f; unsigned int i; } v; v.f = f;
    unsigned int x = v.i;
    return (unsigned short)((x + 0x7fffu + ((x >> 16) & 1u)) >> 16);
}
// fast silu (f32): mul, v_exp_f32, add, v_rcp_f32, mul
__device__ __forceinline__ float silu_f(float x) {
    float e = __builtin_amdgcn_exp2f(-1.44269504088896f * x);
    return x * __builtin_amdgcn_rcpf(1.0f + e);
}
// packed f16 silu on a half2 pair: 3 pk-VALU + 4 trans (v_exp_f16/v_rcp_f16)
__device__ __forceinline__ __half2 silu_h2(__half2 x, __half2 kf, __half2 one2) {
    __half2 e = h2exp2(__hmul2(x, kf));
    return __hmul2(x, h2rcp(__hadd2(one2, e)));
}

struct Ptrs { const void* p[14]; };
// p: 0 pos, 1 embed, 2 ew1, 3 eb1, 4 ew2, 5 eb2, 6 nw1, 7 nb1, 8 nw2,
//    9 nb2, 10 lng, 11 lnb, 12 ow, 13 ob

__device__ __forceinline__ float ldf(const void* p, int i, int bf) {
    return bf ? bf2f(((const unsigned short*)p)[i]) : ((const float*)p)[i];
}

// small canon (fp32) offsets: pos 0(12288) embed 12288(1280) wd 13568(512)
// eb1 14080 eb2 14592 nb1 15104 nb2 15616 lng 16128 lnb 16640 (512 each)
// ow 17152(384) ob 17536(3). total 17539.
#define SWZ_TOTAL 393216
#define SMALL_TOTAL 17539

// Swizzle weights into f16 B-fragment order for mfma_f32_16x16x32_f16:
//   dst[((s*8+c)*64+l)*8 + j] = W[s*32 + (l>>4)*8 + j][c*16 + (l&15)]
// Per-layer: wa@0 wb@16K ew2@32K nw1@48K(32K) nw2@80K; stride 98304.
__global__ __launch_bounds__(256) void prep_kernel(
    Ptrs ptrs, f16* dst, float* sc)
{
    __shared__ int flgsh;
    int t = threadIdx.x;
    if (t < 64) {
        int ex = (((const unsigned short*)ptrs.p[0])[t * 2] >> 7) & 0xFF;
        unsigned long long m = __ballot(ex >= 110 && ex <= 135);
        if (t == 0) flgsh = (__popcll(m) >= 40) ? 1 : 0;
    }
    __syncthreads();
    int bf = flgsh;

    int gid = blockIdx.x * 256 + t;
    if (gid < SWZ_TOTAL) {
        int lay = gid / 98304;
        int r   = gid % 98304;
        const void* src; int base, rowoff = 0, r2;
        if (r < 49152) {
            int mat = r >> 14; r2 = r & 16383;
            if (mat == 0)      { src = ptrs.p[2]; base = lay * 32896; }
            else if (mat == 1) { src = ptrs.p[2]; base = lay * 32896; rowoff = 128; }
            else               { src = ptrs.p[4]; base = lay * 16384; }
        } else if (r < 81920) {
            r2 = r - 49152; src = ptrs.p[6]; base = lay * 32768;
        } else {
            r2 = r - 81920; src = ptrs.p[8]; base = lay * 16384;
        }
        int s = r2 >> 12, q = r2 & 4095;
        int j = q & 7, l = (q >> 3) & 63, c = q >> 9;
        int row = rowoff + s * 32 + ((l >> 4) << 3) + j;
        int col = (c << 4) + (l & 15);
        dst[gid] = (f16)ldf(src, base + row * 128 + col, bf);
    } else {
        int sid = gid - SWZ_TOTAL;
        if (sid >= SMALL_TOTAL) return;
        const void* src; int i;
        if      (sid < 12288) { src = ptrs.p[0]; i = sid; }
        else if (sid < 13568) { src = ptrs.p[1]; i = sid - 12288; }
        else if (sid < 14080) { int k = sid - 13568;
                                src = ptrs.p[2]; i = (k >> 7) * 32896 + 32768 + (k & 127); }
        else if (sid < 14592) { src = ptrs.p[3];  i = sid - 14080; }
        else if (sid < 15104) { src = ptrs.p[5];  i = sid - 14592; }
        else if (sid < 15616) { src = ptrs.p[7];  i = sid - 15104; }
        else if (sid < 16128) { src = ptrs.p[9];  i = sid - 15616; }
        else if (sid < 16640) { src = ptrs.p[10]; i = sid - 16128; }
        else if (sid < 17152) { src = ptrs.p[11]; i = sid - 16640; }
        else if (sid < 17536) { src = ptrs.p[12]; i = sid - 17152; }
        else                  { src = ptrs.p[13]; i = sid - 17536; }
        sc[sid] = ldf(src, i, bf);
    }
}

// h = embed[an]; a = h@wa + eb1; b = h@wb.
// 256 threads / 16 rows: wave w computes output cols c = 2w, 2w+1 (both mats).
__global__ __launch_bounds__(256) void embed_ab_kernel(
    const int* an, const float* sc, const f16* wa, const f16* wb,
    const float* eb1C, f16* h16, f16* a16, f16* b16)
{
    int t = threadIdx.x;
    int w = t >> 6, lane = t & 63;
    int row0 = blockIdx.x << 4;
    int m_ = lane & 15, q_ = lane >> 4;
    const float* emb = sc + 12288;
    int a = an[row0 + m_];
    a = a < 0 ? 0 : (a > 9 ? 9 : a);
    f16x8 afrag[4];
#pragma unroll
    for (int s = 0; s < 4; s++) {
        f32x4 u0 = *(const f32x4*)(emb + a * 128 + s * 32 + q_ * 8);
        f32x4 u1 = *(const f32x4*)(emb + a * 128 + s * 32 + q_ * 8 + 4);
        f16x8 hv;
#pragma unroll
        for (int e = 0; e < 4; e++) { hv[e] = (f16)u0[e]; hv[e + 4] = (f16)u1[e]; }
        afrag[s] = hv;
        if (w == 0)
            *(f16x8*)(h16 + (row0 + m_) * 128 + s * 32 + q_ * 8) = hv;
    }
#pragma unroll
    for (int mat = 0; mat < 2; mat++) {
        const f16* W = mat ? wb : wa;
        f16* out     = mat ? b16 : a16;
#pragma unroll
        for (int cc = 0; cc < 2; cc++) {
            int c = 2 * w + cc;
            float init = mat ? 0.0f : eb1C[c * 16 + m_];
            f32x4 acc = { init, init, init, init };
#pragma unroll
            for (int s = 0; s < 4; s++) {
                f16x8 bfr = *(const f16x8*)(W + ((s * 8 + c) * 64 + lane) * 8);
                acc = __builtin_amdgcn_mfma_f32_16x16x32_f16(afrag[s], bfr, acc, 0, 0, 0);
            }
#pragma unroll
            for (int r = 0; r < 4; r++)
                out[(row0 + q_ * 4 + r) * 128 + c * 16 + m_] = (f16)acc[r];
        }
    }
}

// Block per (b,i): m_i = mean_j silu(silu(pre_ij) @ ew2 + eb2)
// r6-proven skeleton (2-phase ew2 staging, msum overlay) with:
//  - 2x2 wave split: wave (wr,wc) = rows [wr*32,+32) x cols [wc*64,+64)
//    -> GEMM ds_read_b128 36->24 per wave
//  - packed __half2 S-build (v_pk_* + v_exp_f16/v_rcp_f16), f16x8 loads
__global__ __launch_bounds__(256) void edge_kernel(
    const float* sc, const f16* a16, const f16* b16,
    const f16* ew2_swz, const float* eb2C, const float* wdC, f16* m_out)
{
    __shared__ f16 Wlds[8192];         // half of swizzled ew2, 16 KB
    __shared__ f16 S[64 * 136];        // silu(pre), stride 136
    __shared__ __half2 wd2_sh[64];
    __shared__ float dsq_sh[64];

    int t  = threadIdx.x;
    int ig = blockIdx.x;               // b*64 + i
    int b  = ig >> 6;
    const float* posC = sc;

    // stage half A: fragments s=0,1 == ew2_swz[0..8191]
#pragma unroll
    for (int k = 0; k < 4; k++) {
        int idx = (k * 256 + t) * 8;
        *(f16x8*)(Wlds + idx) = *(const f16x8*)(ew2_swz + idx);
    }
    if (t >= 64 && t < 128) {
        int u = t - 64;
        wd2_sh[u] = __floats2half2_rn(wdC[2 * u], wdC[2 * u + 1]);
    }
    if (t < 64) {
        float xi = posC[ig * 3 + 0], yi = posC[ig * 3 + 1], zi = posC[ig * 3 + 2];
        int jg = b * 64 + t;
        float dx = xi - posC[jg * 3 + 0];
        float dy = yi - posC[jg * 3 + 1];
        float dz = zi - posC[jg * 3 + 2];
        dsq_sh[t] = dx * dx + dy * dy + dz * dz;
    }
    __syncthreads();

    // S[j][d] = silu(a_i[d] + b_j[d] + dsq[j]*wd[d]) — packed f16.
    // thread -> row j = t>>2, cols [(t&3)*32, +32)
    {
        int j  = t >> 2;
        int cb = (t & 3) * 32;
        float dsf = dsq_sh[j];
        __half dh = __float2half_rn(dsf);
        __half2 ds2 = __halves2half2(dh, dh);
        __half2 kf   = __floats2half2_rn(-1.44269504f, -1.44269504f);
        __half2 one2 = __floats2half2_rn(1.0f, 1.0f);
        H2x4 a_r[4], wd_r[4];
#pragma unroll
        for (int k = 0; k < 4; k++) {
            a_r[k].v  = *(const f16x8*)(a16 + ig * 128 + cb + k * 8);
            wd_r[k].v = *(const f16x8*)((const f16*)wd2_sh + cb + k * 8);
        }
#pragma unroll
        for (int k = 0; k < 4; k++) {
            H2x4 bv, sv;
            bv.v = *(const f16x8*)(b16 + (b * 64 + j) * 128 + cb + k * 8);
#pragma unroll
            for (int e = 0; e < 4; e++) {
                __half2 pre = __hfma2(ds2, wd_r[k].h[e],
                                      __hadd2(a_r[k].h[e], bv.h[e]));
                sv.h[e] = silu_h2(pre, kf, one2);
            }
            *(f16x8*)(S + j * 136 + cb + k * 8) = sv.v;
        }
    }
    __syncthreads();

    // GEMM 64x128 @ 128x128, 2x2 split:
    // wave w: wr=w&1 (rows wr*32..+32), wc=w>>1 (col tiles wc*4..wc*4+3)
    int lane = t & 63, w = t >> 6;
    int wr = w & 1, wc = w >> 1;
    int m_ = lane & 15, q_ = lane >> 4;
    f32x4 acc[4][2];
#pragma unroll
    for (int c = 0; c < 4; c++) {
        float e = eb2C[(wc * 4 + c) * 16 + m_];
        acc[c][0] = (f32x4){ e, e, e, e };
        acc[c][1] = (f32x4){ e, e, e, e };
    }
    // phase 1: s = 0,1
#pragma unroll
    for (int s = 0; s < 2; s++) {
        f16x8 bfr[4];
#pragma unroll
        for (int c = 0; c < 4; c++)
            bfr[c] = *(const f16x8*)(Wlds + ((s * 8 + wc * 4 + c) * 64 + lane) * 8);
#pragma unroll
        for (int mb = 0; mb < 2; mb++) {
            f16x8 af = *(const f16x8*)(S + ((wr * 2 + mb) * 16 + m_) * 136 + s * 32 + q_ * 8);
#pragma unroll
            for (int c = 0; c < 4; c++)
                acc[c][mb] = __builtin_amdgcn_mfma_f32_16x16x32_f16(af, bfr[c], acc[c][mb], 0, 0, 0);
        }
    }
    __syncthreads();                   // all waves done reading half A
    // stage half B: fragments s=2,3 == ew2_swz[8192..16383]
#pragma unroll
    for (int k = 0; k < 4; k++) {
        int idx = (k * 256 + t) * 8;
        *(f16x8*)(Wlds + idx) = *(const f16x8*)(ew2_swz + 8192 + idx);
    }
    __syncthreads();
    // phase 2: s = 2,3 (staged at offset -8192 elements)
#pragma unroll
    for (int s = 2; s < 4; s++) {
        f16x8 bfr[4];
#pragma unroll
        for (int c = 0; c < 4; c++)
            bfr[c] = *(const f16x8*)(Wlds + (((s - 2) * 8 + wc * 4 + c) * 64 + lane) * 8);
#pragma unroll
        for (int mb = 0; mb < 2; mb++) {
            f16x8 af = *(const f16x8*)(S + ((wr * 2 + mb) * 16 + m_) * 136 + s * 32 + q_ * 8);
#pragma unroll
            for (int c = 0; c < 4; c++)
                acc[c][mb] = __builtin_amdgcn_mfma_f32_16x16x32_f16(af, bfr[c], acc[c][mb], 0, 0, 0);
        }
    }
    // silu + sum over this wave's 32 rows (mb,r in-register, q_ via shfl)
    float scv4[4];
#pragma unroll
    for (int c = 0; c < 4; c++) {
        float scv = 0.0f;
#pragma unroll
        for (int mb = 0; mb < 2; mb++)
#pragma unroll
            for (int r = 0; r < 4; r++)
                scv += silu_f(acc[c][mb][r]);
        scv += __shfl_xor(scv, 16);
        scv += __shfl_xor(scv, 32);
        scv4[c] = scv;
    }
    __syncthreads();                   // all waves done reading S
    float* msum = (float*)S;           // overlay: 2 x 128 floats = 1 KB
    if (lane < 16) {
#pragma unroll
        for (int c = 0; c < 4; c++)
            msum[wr * 128 + (wc * 4 + c) * 16 + lane] = scv4[c];
    }
    __syncthreads();
    if (t < 128) {
        float mv = (msum[t] + msum[128 + t]) * (1.0f / 64.0f);
        m_out[ig * 128 + t] = (f16)mv;
    }
}

// Fused node update, 256 threads / 16 rows, column-split across 4 waves:
// u=silu([h|m]@nw1+nb1); x=h+u@nw2+nb2; h'=LN(x)*g+b; next a,b.
__global__ __launch_bounds__(256) void node_mid_kernel(
    const f16* h16, const f16* m16, const f16* nw1s, const f16* nw2s,
    const float* nb1C, const float* nb2C, const float* lngC, const float* lnbC,
    const f16* waN, const f16* wbN, const float* eb1N,
    f16* a16, f16* b16)
{
    __shared__ f16 relay[16 * 136];
    __shared__ float s1sh[4][16], s2sh[4][16];
    int t = threadIdx.x;
    int w = t >> 6, lane = t & 63;
    int row0 = blockIdx.x << 4;
    int m_ = lane & 15, q_ = lane >> 4;

    f16x8 af[8];
#pragma unroll
    for (int s = 0; s < 4; s++) {
        af[s]     = *(const f16x8*)(h16 + (row0 + m_) * 128 + s * 32 + q_ * 8);
        af[s + 4] = *(const f16x8*)(m16 + (row0 + m_) * 128 + s * 32 + q_ * 8);
    }
    // n1: wave w -> cols c = 2w, 2w+1
#pragma unroll
    for (int cc = 0; cc < 2; cc++) {
        int c = 2 * w + cc;
        float e = nb1C[c * 16 + m_];
        f32x4 acc = { e, e, e, e };
#pragma unroll
        for (int s = 0; s < 8; s++) {
            f16x8 bfr = *(const f16x8*)(nw1s + ((s * 8 + c) * 64 + lane) * 8);
            acc = __builtin_amdgcn_mfma_f32_16x16x32_f16(af[s], bfr, acc, 0, 0, 0);
        }
#pragma unroll
        for (int r = 0; r < 4; r++)
            relay[(q_ * 4 + r) * 136 + c * 16 + m_] = (f16)silu_f(acc[r]);
    }
    __syncthreads();
    f16x8 uf[4];
#pragma unroll
    for (int s = 0; s < 4; s++)
        uf[s] = *(const f16x8*)(relay + m_ * 136 + s * 32 + q_ * 8);
    // n2 + residual (this wave's 2 cols only)
    float x[2][4];
#pragma unroll
    for (int cc = 0; cc < 2; cc++) {
        int c = 2 * w + cc;
        float e = nb2C[c * 16 + m_];
        f32x4 acc = { e, e, e, e };
#pragma unroll
        for (int s = 0; s < 4; s++) {
            f16x8 bfr = *(const f16x8*)(nw2s + ((s * 8 + c) * 64 + lane) * 8);
            acc = __builtin_amdgcn_mfma_f32_16x16x32_f16(uf[s], bfr, acc, 0, 0, 0);
        }
#pragma unroll
        for (int r = 0; r < 4; r++)
            x[cc][r] = acc[r] + (float)h16[(row0 + q_ * 4 + r) * 128 + c * 16 + m_];
    }
    // LN: per-row partials over this wave's 2 cols, reduce over m_ then waves
    float s1p[4], s2p[4];
#pragma unroll
    for (int r = 0; r < 4; r++) {
        s1p[r] = x[0][r] + x[1][r];
        s2p[r] = x[0][r] * x[0][r] + x[1][r] * x[1][r];
    }
#pragma unroll
    for (int msk = 1; msk < 16; msk <<= 1)
#pragma unroll
        for (int r = 0; r < 4; r++) {
            s1p[r] += __shfl_xor(s1p[r], msk);
            s2p[r] += __shfl_xor(s2p[r], msk);
        }
    if (m_ == 0)
#pragma unroll
        for (int r = 0; r < 4; r++) {
            s1sh[w][q_ * 4 + r] = s1p[r];
            s2sh[w][q_ * 4 + r] = s2p[r];
        }
    __syncthreads();
    float mu[4], rs[4];
#pragma unroll
    for (int r = 0; r < 4; r++) {
        int row = q_ * 4 + r;
        float S1 = s1sh[0][row] + s1sh[1][row] + s1sh[2][row] + s1sh[3][row];
        float S2 = s2sh[0][row] + s2sh[1][row] + s2sh[2][row] + s2sh[3][row];
        mu[r] = S1 * (1.0f / 128.0f);
        float var = S2 * (1.0f / 128.0f) - mu[r] * mu[r];
        rs[r] = rsqrtf(var + 1e-5f);
    }
#pragma unroll
    for (int cc = 0; cc < 2; cc++) {
        int c = 2 * w + cc;
#pragma unroll
        for (int r = 0; r < 4; r++) {
            int col = c * 16 + m_;
            int row = row0 + q_ * 4 + r;
            float y = (x[cc][r] - mu[r]) * rs[r] * lngC[col] + lnbC[col];
            ((f16*)h16)[row * 128 + col] = (f16)y;
            relay[(q_ * 4 + r) * 136 + col] = (f16)y;
        }
    }
    __syncthreads();
    f16x8 hf[4];
#pragma unroll
    for (int s = 0; s < 4; s++)
        hf[s] = *(const f16x8*)(relay + m_ * 136 + s * 32 + q_ * 8);
    // next layer a,b (this wave's 2 cols)
#pragma unroll
    for (int mat = 0; mat < 2; mat++) {
        const f16* W = mat ? wbN : waN;
        f16* out     = mat ? b16 : a16;
#pragma unroll
        for (int cc = 0; cc < 2; cc++) {
            int c = 2 * w + cc;
            float init = mat ? 0.0f : eb1N[c * 16 + m_];
            f32x4 acc = { init, init, init, init };
#pragma unroll
            for (int s = 0; s < 4; s++) {
                f16x8 bfr = *(const f16x8*)(W + ((s * 8 + c) * 64 + lane) * 8);
                acc = __builtin_amdgcn_mfma_f32_16x16x32_f16(hf[s], bfr, acc, 0, 0, 0);
            }
#pragma unroll
            for (int r = 0; r < 4; r++)
                out[(row0 + q_ * 4 + r) * 128 + c * 16 + m_] = (f16)acc[r];
        }
    }
}

// Last layer: node update then out = h'@ow + ob. Same 256-thread split.
__global__ __launch_bounds__(256) void node_final_kernel(
    const void* pos_raw, const f16* h16, const f16* m16,
    const f16* nw1s, const f16* nw2s,
    const float* nb1C, const float* nb2C, const float* lngC, const float* lnbC,
    const float* owC, const float* obC, void* out)
{
    __shared__ f16 relay[16 * 136];
    __shared__ float s1sh[4][16], s2sh[4][16];
    __shared__ float psh[4][16][3];
    __shared__ int flgsh;
    int t = threadIdx.x;
    int w = t >> 6, lane = t & 63;
    int row0 = blockIdx.x << 4;
    int m_ = lane & 15, q_ = lane >> 4;

    if (t < 64) {
        int ex = (((const unsigned short*)pos_raw)[t * 2] >> 7) & 0xFF;
        unsigned long long mk = __ballot(ex >= 110 && ex <= 135);
        if (t == 0) flgsh = (__popcll(mk) >= 40) ? 1 : 0;
    }

    f16x8 af[8];
#pragma unroll
    for (int s = 0; s < 4; s++) {
        af[s]     = *(const f16x8*)(h16 + (row0 + m_) * 128 + s * 32 + q_ * 8);
        af[s + 4] = *(const f16x8*)(m16 + (row0 + m_) * 128 + s * 32 + q_ * 8);
    }
#pragma unroll
    for (int cc = 0; cc < 2; cc++) {
        int c = 2 * w + cc;
        float e = nb1C[c * 16 + m_];
        f32x4 acc = { e, e, e, e };
#pragma unroll
        for (int s = 0; s < 8; s++) {
            f16x8 bfr = *(const f16x8*)(nw1s + ((s * 8 + c) * 64 + lane) * 8);
            acc = __builtin_amdgcn_mfma_f32_16x16x32_f16(af[s], bfr, acc, 0, 0, 0);
        }
#pragma unroll
        for (int r = 0; r < 4; r++)
            relay[(q_ * 4 + r) * 136 + c * 16 + m_] = (f16)silu_f(acc[r]);
    }
    __syncthreads();
    f16x8 uf[4];
#pragma unroll
    for (int s = 0; s < 4; s++)
        uf[s] = *(const f16x8*)(relay + m_ * 136 + s * 32 + q_ * 8);
    float x[2][4];
#pragma unroll
    for (int cc = 0; cc < 2; cc++) {
        int c = 2 * w + cc;
        float e = nb2C[c * 16 + m_];
        f32x4 acc = { e, e, e, e };
#pragma unroll
        for (int s = 0; s < 4; s++) {
            f16x8 bfr = *(const f16x8*)(nw2s + ((s * 8 + c) * 64 + lane) * 8);
            acc = __builtin_amdgcn_mfma_f32_16x16x32_f16(uf[s], bfr, acc, 0, 0, 0);
        }
#pragma unroll
        for (int r = 0; r < 4; r++)
            x[cc][r] = acc[r] + (float)h16[(row0 + q_ * 4 + r) * 128 + c * 16 + m_];
    }
    float s1p[4], s2p[4];
#pragma unroll
    for (int r = 0; r < 4; r++) {
        s1p[r] = x[0][r] + x[1][r];
        s2p[r] = x[0][r] * x[0][r] + x[1][r] * x[1][r];
    }
#pragma unroll
    for (int msk = 1; msk < 16; msk <<= 1)
#pragma unroll
        for (int r = 0; r < 4; r++) {
            s1p[r] += __shfl_xor(s1p[r], msk);
            s2p[r] += __shfl_xor(s2p[r], msk);
        }
    if (m_ == 0)
#pragma unroll
        for (int r = 0; r < 4; r++) {
            s1sh[w][q_ * 4 + r] = s1p[r];
            s2sh[w][q_ * 4 + r] = s2p[r];
        }
    __syncthreads();
    // out projection: per-row partials over this wave's 2 cols
    float p[3][4];
#pragma unroll
    for (int r = 0; r < 4; r++) {
        int row = q_ * 4 + r;
        float S1 = s1sh[0][row] + s1sh[1][row] + s1sh[2][row] + s1sh[3][row];
        float S2 = s2sh[0][row] + s2sh[1][row] + s2sh[2][row] + s2sh[3][row];
        float mu = S1 * (1.0f / 128.0f);
        float var = S2 * (1.0f / 128.0f) - mu * mu;
        float rs = rsqrtf(var + 1e-5f);
        float p0 = 0.0f, p1 = 0.0f, p2 = 0.0f;
#pragma unroll
        for (int cc = 0; cc < 2; cc++) {
            int col = (2 * w + cc) * 16 + m_;
            float y = (x[cc][r] - mu) * rs * lngC[col] + lnbC[col];
            p0 += y * owC[col * 3 + 0];
            p1 += y * owC[col * 3 + 1];
            p2 += y * owC[col * 3 + 2];
        }
        p[0][r] = p0; p[1][r] = p1; p[2][r] = p2;
    }
#pragma unroll
    for (int msk = 1; msk < 16; msk <<= 1)
#pragma unroll
        for (int k = 0; k < 3; k++)
#pragma unroll
            for (int r = 0; r < 4; r++)
                p[k][r] += __shfl_xor(p[k][r], msk);
    if (m_ == 0)
#pragma unroll
        for (int r = 0; r < 4; r++)
#pragma unroll
            for (int k = 0; k < 3; k++)
                psh[w][q_ * 4 + r][k] = p[k][r];
    __syncthreads();
    if (t < 16) {
        int row = row0 + t;
        int bf = flgsh;
#pragma unroll
        for (int k = 0; k < 3; k++) {
            float v = psh[0][t][k] + psh[1][t][k] + psh[2][t][k] + psh[3][t][k]
                      + obC[k];
            if (bf) ((unsigned short*)out)[row * 3 + k] = f2bf(v);
            else    ((float*)out)[row * 3 + k] = v;
        }
    }
}

extern "C" void kernel_launch(void* const* d_in, const int* in_sizes, int n_in,
                              void* d_out, int out_size, void* d_ws, size_t ws_size,
                              hipStream_t stream)
{
    const int* an = (const int*)d_in[1];

    char* ws = (char*)d_ws;
    float* sc   = (float*)(ws + 1024);              // 70 KB
    f16*   Wswz = (f16*)(ws + (128u << 10));        // 768 KB
    f16*   h16  = (f16*)(ws + (1u << 20));          // 1 MB
    f16*   a16  = (f16*)(ws + (2u << 20));
    f16*   b16  = (f16*)(ws + (3u << 20));
    f16*   m16  = (f16*)(ws + (4u << 20));          // total 5 MB

    Ptrs ptrs;
    const int src_idx[14] = {0, 2, 3, 4, 5, 6, 7, 8, 9, 10, 11, 12, 13, 14};
    for (int k = 0; k < 14; k++) ptrs.p[k] = d_in[src_idx[k]];

    prep_kernel<<<1605, 256, 0, stream>>>(ptrs, Wswz, sc);
    embed_ab_kernel<<<256, 256, 0, stream>>>(an, sc, Wswz, Wswz + 16384,
                                             sc + 14080, h16, a16, b16);
    for (int lay = 0; lay < 4; lay++) {
        const f16* wl = Wswz + lay * 98304;
        const float* wdC  = sc + 13568 + lay * 128;
        const float* eb2C = sc + 14592 + lay * 128;
        const float* nb1C = sc + 15104 + lay * 128;
        const float* nb2C = sc + 15616 + lay * 128;
        const float* lngC = sc + 16128 + lay * 128;
        const float* lnbC = sc + 16640 + lay * 128;

        edge_kernel<<<4096, 256, 0, stream>>>(sc, a16, b16, wl + 32768,
                                              eb2C, wdC, m16);
        if (lay < 3) {
            const f16* wlN = Wswz + (lay + 1) * 98304;
            node_mid_kernel<<<256, 256, 0, stream>>>(
                h16, m16, wl + 49152, wl + 81920, nb1C, nb2C, lngC, lnbC,
                wlN, wlN + 16384, sc + 14080 + (lay + 1) * 128, a16, b16);
        } else {
            node_final_kernel<<<256, 256, 0, stream>>>(
                d_in[0], h16, m16, wl + 49152, wl + 81920,
                nb1C, nb2C, lngC, lnbC,
                sc + 17152, sc + 17536, d_out);
        }
    }
}